// Round 12
// baseline (522.126 us; speedup 1.0000x reference)
//
#include <hip/hip_runtime.h>

typedef unsigned short u16;
typedef unsigned int u32;
typedef __bf16 bf16x8 __attribute__((ext_vector_type(8)));
typedef float f32x4 __attribute__((ext_vector_type(4)));
typedef float f32x16 __attribute__((ext_vector_type(16)));
typedef u16 u16x8 __attribute__((ext_vector_type(8)));
typedef u32 u32x4 __attribute__((ext_vector_type(4)));

// ---------------- helpers ----------------
__device__ __forceinline__ u16 f2bf(float f) {
  union { float f; unsigned u; } x; x.f = f;
  unsigned r = x.u + 0x7FFFu + ((x.u >> 16) & 1u);
  return (u16)(r >> 16);
}
__device__ __forceinline__ float bf2f(u16 h) {
  union { unsigned u; float f; } x; x.u = ((unsigned)h) << 16;
  return x.f;
}
__device__ __forceinline__ void gload_lds16(const void* gptr, const void* lptr) {
  int m0v = __builtin_amdgcn_readfirstlane((int)(unsigned)(size_t)lptr);
  asm volatile("s_mov_b32 m0, %0\n\t"
               "global_load_lds_dwordx4 %1, off\n\t"
               :: "s"(m0v), "v"(gptr) : "memory");
}
__device__ __forceinline__ f32x16 zero16() {
  f32x16 x;
#pragma unroll
  for (int i = 0; i < 16; ++i) x[i] = 0.f;
  return x;
}

// ---------------- weight transpose+convert: f32 [K][N] -> bf16 [N][K] ----------------
__global__ __launch_bounds__(256) void wtrans_k(const float* __restrict__ in,
                                                u16* __restrict__ out, int K, int N,
                                                int qcols, float qscale) {
  __shared__ u16 tile[64 * 72];
  int t = threadIdx.x;
  int kb = blockIdx.y << 6, nb = blockIdx.x << 6;
  float sc = (nb < qcols) ? qscale : 1.f;
  int cg = t & 15, r0 = t >> 4;
  for (int i = 0; i < 4; ++i) {
    int k = r0 + (i << 4);
    float4 v = *reinterpret_cast<const float4*>(in + (size_t)(kb + k) * N + nb + (cg << 2));
    tile[(cg * 4 + 0) * 72 + k] = f2bf(v.x * sc);
    tile[(cg * 4 + 1) * 72 + k] = f2bf(v.y * sc);
    tile[(cg * 4 + 2) * 72 + k] = f2bf(v.z * sc);
    tile[(cg * 4 + 3) * 72 + k] = f2bf(v.w * sc);
  }
  __syncthreads();
  int kg = t & 7, n0 = t >> 3;
  for (int i = 0; i < 2; ++i) {
    int n = n0 + (i << 5);
    u16x8 val = *reinterpret_cast<const u16x8*>(&tile[n * 72 + (kg << 3)]);
    *reinterpret_cast<u16x8*>(out + (size_t)(nb + n) * K + kb + (kg << 3)) = val;
  }
}

// ---------------- LayerNorm: f32 [R][D] -> bf16 [R][D] ----------------
__global__ __launch_bounds__(256) void ln_k(const float* __restrict__ x,
                                            const float* __restrict__ gam,
                                            const float* __restrict__ bet,
                                            u16* __restrict__ out, int D) {
  int row = blockIdx.x, t = threadIdx.x;
  const float* xr = x + (size_t)row * D;
  int E = D >> 8;
  float v[8];
  float s = 0.f, sq = 0.f;
  for (int j = 0; j < E; ++j) {
    float f = xr[t + (j << 8)];
    v[j] = f; s += f; sq += f * f;
  }
  for (int m = 32; m; m >>= 1) { s += __shfl_xor(s, m); sq += __shfl_xor(sq, m); }
  __shared__ float red[10];
  int wid = t >> 6;
  if ((t & 63) == 0) { red[wid] = s; red[wid + 4] = sq; }
  __syncthreads();
  if (t == 0) {
    float S = red[0] + red[1] + red[2] + red[3];
    float Q = red[4] + red[5] + red[6] + red[7];
    float mean = S / (float)D;
    float var = Q / (float)D - mean * mean;
    red[8] = mean; red[9] = rsqrtf(var + 1e-5f);
  }
  __syncthreads();
  float mean = red[8], rstd = red[9];
  u16* orow = out + (size_t)row * D;
  for (int j = 0; j < E; ++j) {
    int idx = t + (j << 8);
    orow[idx] = f2bf((v[j] - mean) * rstd * gam[idx] + bet[idx]);
  }
}

// ---------------- GEMM: C[M][N] = A[M][K](bf16) @ Wt[N][K](bf16)^T, 128xBN tile --------------
// 3-buffer 2-ahead pipeline, counted vmcnt, raw barriers, slot-XOR swizzle
// (conflict-free), XCD-chunked swizzle. BN in {128, 64}.
struct GemmArgs {
  const u16* A; const u16* W;
  int M, N, K;
  int Nm, tokoff;
  const float* bias;
  const float* resid;
  float* outF;
  u16* outB;
  u16* q; u16* kk; u16* v;
  int cswz;
};
__device__ __forceinline__ int maprow_o(int r, int Nm, int tokoff) {
  int b = (r >= Nm) ? 1 : 0;
  return b * 1920 + tokoff + (r - b * Nm);
}

template <int MODE, int BN>
__global__ __launch_bounds__(256) void gemm_k(GemmArgs g) {
  constexpr int NF = BN / 32;
  __shared__ u16 As[3][128 * 32];
  __shared__ u16 Ws[3][BN * 32];
  int t = threadIdx.x, lane = t & 63, wid = t >> 6;

  int nwg = gridDim.x * gridDim.y;
  int wgid = blockIdx.y * gridDim.x + blockIdx.x;
  int q8 = nwg >> 3, r8 = nwg & 7;
  int xcd = wgid & 7, loc = wgid >> 3;
  int nid = (xcd < r8 ? xcd * (q8 + 1) : r8 * (q8 + 1) + (xcd - r8) * q8) + loc;
  constexpr int BNSH = (BN == 128) ? 7 : 6;
  int bm, bn;
  if (g.cswz) { bn = (nid / gridDim.y) << BNSH; bm = (nid % gridDim.y) << 7; }
  else        { bm = (nid / gridDim.x) << 7;    bn = (nid % gridDim.x) << BNSH; }

  int wr = wid >> 1, wc = wid & 1;
  int fr = lane & 15, fq = lane >> 4;

  f32x4 z = {0.f, 0.f, 0.f, 0.f};
  f32x4 acc[4][NF];
#pragma unroll
  for (int m = 0; m < 4; ++m)
#pragma unroll
    for (int n = 0; n < NF; ++n) acc[m][n] = z;

  int srow = wid * 16 + (lane >> 2);
  int scolz = (((lane & 3) ^ ((lane >> 3) & 3)) << 3);
  int ar0 = bm + srow, ar1 = bm + srow + 64;
  if (MODE == 1) { ar0 = maprow_o(ar0, g.Nm, g.tokoff); ar1 = maprow_o(ar1, g.Nm, g.tokoff); }
  const u16* Ap0 = g.A + (size_t)ar0 * g.K + scolz;
  const u16* Ap1 = g.A + (size_t)ar1 * g.K + scolz;
  const u16* Wp0 = g.W + (size_t)(bn + srow) * g.K + scolz;
  const u16* Wp1 = g.W + (size_t)(bn + srow + 64) * g.K + scolz;
  const int soff = (wid * 16) * 32;

  const int sl8 = ((fq ^ ((fr >> 1) & 3)) << 3);

#define STAGE(buf, kt)                                                    \
  do {                                                                    \
    gload_lds16(Ap0 + ((kt) << 5), &As[buf][soff]);                       \
    gload_lds16(Ap1 + ((kt) << 5), &As[buf][soff + 64 * 32]);             \
    gload_lds16(Wp0 + ((kt) << 5), &Ws[buf][soff]);                       \
    if constexpr (BN == 128)                                              \
      gload_lds16(Wp1 + ((kt) << 5), &Ws[buf][soff + 64 * 32]);           \
  } while (0)

  int nk = g.K >> 5;
  STAGE(0, 0);
  STAGE(1, 1);
  int cur = 0, stg = 2;
  for (int kt = 0; kt < nk; ++kt) {
    if (kt + 1 < nk) {
      if constexpr (BN == 128) asm volatile("s_waitcnt vmcnt(4)" ::: "memory");
      else                     asm volatile("s_waitcnt vmcnt(3)" ::: "memory");
    } else {
      asm volatile("s_waitcnt vmcnt(0)" ::: "memory");
    }
    __builtin_amdgcn_s_barrier();
    if (kt + 2 < nk) STAGE(stg, kt + 2);
    bf16x8 af[4], bw[NF];
#pragma unroll
    for (int m = 0; m < 4; ++m)
      af[m] = *reinterpret_cast<const bf16x8*>(&As[cur][(wr * 64 + m * 16 + fr) * 32 + sl8]);
#pragma unroll
    for (int n = 0; n < NF; ++n)
      bw[n] = *reinterpret_cast<const bf16x8*>(&Ws[cur][(wc * (BN / 2) + n * 16 + fr) * 32 + sl8]);
    __builtin_amdgcn_s_setprio(1);
#pragma unroll
    for (int m = 0; m < 4; ++m)
#pragma unroll
      for (int n = 0; n < NF; ++n)
        acc[m][n] = __builtin_amdgcn_mfma_f32_16x16x32_bf16(af[m], bw[n], acc[m][n], 0, 0, 0);
    __builtin_amdgcn_s_setprio(0);
    asm volatile("s_waitcnt lgkmcnt(0)" ::: "memory");
    __builtin_amdgcn_sched_barrier(0);
    cur = (cur == 2) ? 0 : cur + 1;
    stg = (stg == 2) ? 0 : stg + 1;
  }
#undef STAGE

#pragma unroll
  for (int m = 0; m < 4; ++m) {
    int rrel = wr * 64 + m * 16 + fq * 4;
#pragma unroll
    for (int n = 0; n < NF; ++n) {
      int c = bn + wc * (BN / 2) + n * 16 + fr;
#pragma unroll
      for (int j = 0; j < 4; ++j) {
        int r = bm + rrel + j;
        float val = acc[m][n][j];
        if constexpr (MODE == 0) {
          int b = (r >= g.Nm) ? 1 : 0;
          int ng = g.tokoff + (r - b * g.Nm);
          int p = c >> 10, h = (c >> 6) & 15, dh = c & 63;
          u16* dst = (p == 0) ? g.q : (p == 1) ? g.kk : g.v;
          dst[(((size_t)(b * 16 + h)) * 1920 + ng) * 64 + dh] = f2bf(val);
        } else if constexpr (MODE == 1) {
          size_t idx = (size_t)r * g.N + c;
          g.outF[idx] = g.resid[idx] + val;
        } else if constexpr (MODE == 2) {
          float hh = val + g.bias[c];
          float ge = 0.5f * hh * (1.f + erff(hh * 0.70710678118f));
          g.outB[(size_t)r * g.N + c] = f2bf(ge);
        } else {
          size_t idx = (size_t)r * g.N + c;
          g.outF[idx] += val + g.bias[c];
        }
      }
    }
  }
}

// ---------------- GEMM3: 256x128 tile, 512 threads (8 waves), 3-buffer 2-ahead ---------------
// Doubles MFMA per barrier and per staged byte vs 128x128; 72 KB LDS -> 2 blocks/CU
// (16 waves/CU). Same counted-vmcnt schedule (3 loads/thread/tile -> steady vmcnt(3)).
template <int MODE>
__global__ __launch_bounds__(512) void gemm3_k(GemmArgs g) {
  __shared__ u16 As[3][256 * 32];
  __shared__ u16 Ws[3][128 * 32];
  int t = threadIdx.x, lane = t & 63, wid = t >> 6;

  int nwg = gridDim.x * gridDim.y;
  int wgid = blockIdx.y * gridDim.x + blockIdx.x;
  int q8 = nwg >> 3, r8 = nwg & 7;
  int xcd = wgid & 7, loc = wgid >> 3;
  int nid = (xcd < r8 ? xcd * (q8 + 1) : r8 * (q8 + 1) + (xcd - r8) * q8) + loc;
  int bm, bn;
  if (g.cswz) { bn = (nid / gridDim.y) << 7; bm = (nid % gridDim.y) << 8; }
  else        { bm = (nid / gridDim.x) << 8; bn = (nid % gridDim.x) << 7; }

  int wr = wid >> 1, wc = wid & 1;   // wr 0..3 (rows of 64), wc 0..1 (cols of 64)
  int fr = lane & 15, fq = lane >> 4;

  f32x4 z = {0.f, 0.f, 0.f, 0.f};
  f32x4 acc[4][4];
#pragma unroll
  for (int m = 0; m < 4; ++m)
#pragma unroll
    for (int n = 0; n < 4; ++n) acc[m][n] = z;

  int srow = wid * 16 + (lane >> 2);          // 0..127
  int scolz = (((lane & 3) ^ ((lane >> 3) & 3)) << 3);
  const u16* Ap0 = g.A + (size_t)(bm + srow) * g.K + scolz;
  const u16* Ap1 = g.A + (size_t)(bm + srow + 128) * g.K + scolz;
  const u16* Wp0 = g.W + (size_t)(bn + srow) * g.K + scolz;
  const int soff = (wid * 16) * 32;

  const int sl8 = ((fq ^ ((fr >> 1) & 3)) << 3);

#define STAGE3(buf, kt)                                            \
  do {                                                             \
    gload_lds16(Ap0 + ((kt) << 5), &As[buf][soff]);                \
    gload_lds16(Ap1 + ((kt) << 5), &As[buf][soff + 128 * 32]);     \
    gload_lds16(Wp0 + ((kt) << 5), &Ws[buf][soff]);                \
  } while (0)

  int nk = g.K >> 5;
  STAGE3(0, 0);
  STAGE3(1, 1);
  int cur = 0, stg = 2;
  for (int kt = 0; kt < nk; ++kt) {
    if (kt + 1 < nk) asm volatile("s_waitcnt vmcnt(3)" ::: "memory");
    else             asm volatile("s_waitcnt vmcnt(0)" ::: "memory");
    __builtin_amdgcn_s_barrier();
    if (kt + 2 < nk) STAGE3(stg, kt + 2);
    bf16x8 af[4], bw[4];
#pragma unroll
    for (int m = 0; m < 4; ++m)
      af[m] = *reinterpret_cast<const bf16x8*>(&As[cur][(wr * 64 + m * 16 + fr) * 32 + sl8]);
#pragma unroll
    for (int n = 0; n < 4; ++n)
      bw[n] = *reinterpret_cast<const bf16x8*>(&Ws[cur][(wc * 64 + n * 16 + fr) * 32 + sl8]);
    __builtin_amdgcn_s_setprio(1);
#pragma unroll
    for (int m = 0; m < 4; ++m)
#pragma unroll
      for (int n = 0; n < 4; ++n)
        acc[m][n] = __builtin_amdgcn_mfma_f32_16x16x32_bf16(af[m], bw[n], acc[m][n], 0, 0, 0);
    __builtin_amdgcn_s_setprio(0);
    asm volatile("s_waitcnt lgkmcnt(0)" ::: "memory");
    __builtin_amdgcn_sched_barrier(0);
    cur = (cur == 2) ? 0 : cur + 1;
    stg = (stg == 2) ? 0 : stg + 1;
  }
#undef STAGE3

#pragma unroll
  for (int m = 0; m < 4; ++m) {
    int rrel = wr * 64 + m * 16 + fq * 4;
#pragma unroll
    for (int n = 0; n < 4; ++n) {
      int c = bn + wc * 64 + n * 16 + fr;
#pragma unroll
      for (int j = 0; j < 4; ++j) {
        int r = bm + rrel + j;
        float val = acc[m][n][j];
        if constexpr (MODE == 0) {
          int b = (r >= g.Nm) ? 1 : 0;
          int ng = g.tokoff + (r - b * g.Nm);
          int p = c >> 10, h = (c >> 6) & 15, dh = c & 63;
          u16* dst = (p == 0) ? g.q : (p == 1) ? g.kk : g.v;
          dst[(((size_t)(b * 16 + h)) * 1920 + ng) * 64 + dh] = f2bf(val);
        } else if constexpr (MODE == 2) {
          float hh = val + g.bias[c];
          float ge = 0.5f * hh * (1.f + erff(hh * 0.70710678118f));
          g.outB[(size_t)r * g.N + c] = f2bf(ge);
        } else {
          size_t idx = (size_t)r * g.N + c;
          g.outF[idx] += val + g.bias[c];
        }
      }
    }
  }
}

// ---------------- flash attention (swapped-operand, 32x32x16 MFMA) ----------------
__global__ __launch_bounds__(256) void attn_k(const u16* __restrict__ qg,
                                              const u16* __restrict__ kg,
                                              const u16* __restrict__ vg,
                                              u16* __restrict__ og) {
  __shared__ u16 Ks[2][64 * 64];
  __shared__ u16 Vt[2][64 * 64];
  int t = threadIdx.x, lane = t & 63, w = t >> 6;
  int h = lane >> 5, li = lane & 31;
  int qt = blockIdx.x, bh = blockIdx.y;
  const u16* qh = qg + (size_t)bh * 1920 * 64;
  const u16* kh = kg + (size_t)bh * 1920 * 64;
  const u16* vh = vg + (size_t)bh * 1920 * 64;

  bf16x8 bq[4];
  {
    int qrow = qt * 128 + w * 32 + li;
#pragma unroll
    for (int c = 0; c < 4; ++c)
      bq[c] = *reinterpret_cast<const bf16x8*>(qh + (size_t)qrow * 64 + c * 16 + h * 8);
  }

  int r = t >> 3;
  int c8 = (t & 7) << 3;
  int kswz = ((t & 7) ^ (r & 7)) << 3;

  {
    u16x8 k0 = *reinterpret_cast<const u16x8*>(kh + (size_t)r * 64 + c8);
    u16x8 k1 = *reinterpret_cast<const u16x8*>(kh + (size_t)(32 + r) * 64 + c8);
    u16x8 v0 = *reinterpret_cast<const u16x8*>(vh + (size_t)r * 64 + c8);
    u16x8 v1 = *reinterpret_cast<const u16x8*>(vh + (size_t)(32 + r) * 64 + c8);
    *reinterpret_cast<u16x8*>(&Ks[0][r * 64 + kswz]) = k0;
    *reinterpret_cast<u16x8*>(&Ks[0][(32 + r) * 64 + kswz]) = k1;
#pragma unroll
    for (int i = 0; i < 8; ++i) {
      int d = c8 + i;
      Vt[0][d * 64 + (((r >> 3) ^ i) << 3) + (r & 7)] = v0[i];
      Vt[0][d * 64 + ((((r >> 3) + 4) ^ i) << 3) + (r & 7)] = v1[i];
    }
  }
  __syncthreads();

  float m_s = -1e30f, l_s = 0.f;
  f32x16 of0 = zero16(), of1 = zero16();

  int cur = 0;
  for (int kt = 0; kt < 30; ++kt) {
    bool notlast = (kt < 29);
    u16x8 kn0, kn1, vn0, vn1;
    if (notlast) {
      const u16* kp = kh + ((size_t)((kt + 1) * 64) + r) * 64 + c8;
      const u16* vp = vh + ((size_t)((kt + 1) * 64) + r) * 64 + c8;
      kn0 = *reinterpret_cast<const u16x8*>(kp);
      kn1 = *reinterpret_cast<const u16x8*>(kp + 32 * 64);
      vn0 = *reinterpret_cast<const u16x8*>(vp);
      vn1 = *reinterpret_cast<const u16x8*>(vp + 32 * 64);
    }

    f32x16 s0 = zero16(), s1 = zero16();
#pragma unroll
    for (int c = 0; c < 4; ++c) {
      int slot = ((c * 2 + h) ^ (li & 7)) << 3;
      bf16x8 ak0 = *reinterpret_cast<const bf16x8*>(&Ks[cur][li * 64 + slot]);
      bf16x8 ak1 = *reinterpret_cast<const bf16x8*>(&Ks[cur][(32 + li) * 64 + slot]);
      s0 = __builtin_amdgcn_mfma_f32_32x32x16_bf16(ak0, bq[c], s0, 0, 0, 0);
      s1 = __builtin_amdgcn_mfma_f32_32x32x16_bf16(ak1, bq[c], s1, 0, 0, 0);
    }

    float mx = s0[0];
#pragma unroll
    for (int i = 1; i < 16; ++i) mx = fmaxf(mx, s0[i]);
#pragma unroll
    for (int i = 0; i < 16; ++i) mx = fmaxf(mx, s1[i]);
    mx = fmaxf(mx, __shfl_xor(mx, 32));

    if (__any(mx > m_s + 11.5f)) {
      float mn = fmaxf(m_s, mx);
      float sc = exp2f(m_s - mn);
      m_s = mn;
      l_s *= sc;
#pragma unroll
      for (int rr = 0; rr < 16; ++rr) {
        float scr = __shfl(sc, (rr & 3) + ((rr >> 2) << 3) + (h << 2));
        of0[rr] *= scr; of1[rr] *= scr;
      }
    }
    float rs = 0.f;
#pragma unroll
    for (int i = 0; i < 16; ++i) { s0[i] = exp2f(s0[i] - m_s); rs += s0[i]; }
#pragma unroll
    for (int i = 0; i < 16; ++i) { s1[i] = exp2f(s1[i] - m_s); rs += s1[i]; }
    rs += __shfl_xor(rs, 32);
    l_s += rs;

    u32 wv[2][4][2];
#pragma unroll
    for (int g = 0; g < 4; ++g)
#pragma unroll
      for (int c2 = 0; c2 < 2; ++c2) {
        asm("v_cvt_pk_bf16_f32 %0, %1, %2"
            : "=v"(wv[0][g][c2]) : "v"(s0[4 * g + 2 * c2]), "v"(s0[4 * g + 2 * c2 + 1]));
        asm("v_cvt_pk_bf16_f32 %0, %1, %2"
            : "=v"(wv[1][g][c2]) : "v"(s1[4 * g + 2 * c2]), "v"(s1[4 * g + 2 * c2 + 1]));
      }
    u32 xr[2][2][2];
#pragma unroll
    for (int kb = 0; kb < 2; ++kb)
#pragma unroll
      for (int e = 0; e < 2; ++e)
#pragma unroll
        for (int c2 = 0; c2 < 2; ++c2) {
          u32 snd = h ? wv[kb][2 * e][c2] : wv[kb][2 * e + 1][c2];
          xr[kb][e][c2] = (u32)__shfl_xor((int)snd, 32);
        }

#pragma unroll
    for (int kc = 0; kc < 4; ++kc) {
      int kb = kc >> 1, e = kc & 1;
      u32x4 au;
      au[0] = h ? xr[kb][e][0] : wv[kb][2 * e][0];
      au[1] = h ? xr[kb][e][1] : wv[kb][2 * e][1];
      au[2] = h ? wv[kb][2 * e + 1][0] : xr[kb][e][0];
      au[3] = h ? wv[kb][2 * e + 1][1] : xr[kb][e][1];
      bf16x8 af = *reinterpret_cast<bf16x8*>(&au);
      int slot = ((kc * 2 + h) ^ (li & 7)) << 3;
      bf16x8 bv0 = *reinterpret_cast<const bf16x8*>(&Vt[cur][li * 64 + slot]);
      bf16x8 bv1 = *reinterpret_cast<const bf16x8*>(&Vt[cur][(32 + li) * 64 + slot]);
      of0 = __builtin_amdgcn_mfma_f32_32x32x16_bf16(af, bv0, of0, 0, 0, 0);
      of1 = __builtin_amdgcn_mfma_f32_32x32x16_bf16(af, bv1, of1, 0, 0, 0);
    }

    if (notlast) {
      *reinterpret_cast<u16x8*>(&Ks[cur ^ 1][r * 64 + kswz]) = kn0;
      *reinterpret_cast<u16x8*>(&Ks[cur ^ 1][(32 + r) * 64 + kswz]) = kn1;
#pragma unroll
      for (int i = 0; i < 8; ++i) {
        int d = c8 + i;
        Vt[cur ^ 1][d * 64 + (((r >> 3) ^ i) << 3) + (r & 7)] = vn0[i];
        Vt[cur ^ 1][d * 64 + ((((r >> 3) + 4) ^ i) << 3) + (r & 7)] = vn1[i];
      }
    }
    __syncthreads();
    cur ^= 1;
  }

  int b = bh >> 4, hd = bh & 15;
#pragma unroll
  for (int rr = 0; rr < 16; ++rr) {
    int qm = (rr & 3) + ((rr >> 2) << 3) + (h << 2);
    float lq = __shfl(l_s, qm);
    float inv = 1.f / lq;
    int row = qt * 128 + w * 32 + qm;
    size_t base = ((size_t)b * 1920 + row) * 1024 + hd * 64;
    og[base + li] = f2bf(of0[rr] * inv);
    og[base + 32 + li] = f2bf(of1[rr] * inv);
  }
}

// ---------------- host ----------------
extern "C" void kernel_launch(void* const* d_in, const int* in_sizes, int n_in,
                              void* d_out, int out_size, void* d_ws, size_t ws_size,
                              hipStream_t stream) {
  const float* text   = (const float*)d_in[0];
  const float* image  = (const float*)d_in[1];
  const float* action = (const float*)d_in[2];
  const float* t_g = (const float*)d_in[4];
  const float* t_b = (const float*)d_in[5];
  const float* i_g = (const float*)d_in[6];
  const float* i_b = (const float*)d_in[7];
  const float* a_g = (const float*)d_in[8];
  const float* a_b = (const float*)d_in[9];
  const float* i_ffg = (const float*)d_in[10];
  const float* i_ffb = (const float*)d_in[11];
  const float* a_ffg = (const float*)d_in[12];
  const float* a_ffb = (const float*)d_in[13];
  const float* qkv_w_t = (const float*)d_in[14];
  const float* qkv_w_i = (const float*)d_in[15];
  const float* qkv_w_a = (const float*)d_in[16];
  const float* out_w_t = (const float*)d_in[17];
  const float* out_w_i = (const float*)d_in[18];
  const float* out_w_a = (const float*)d_in[19];
  const float* i_ff_w1 = (const float*)d_in[20];
  const float* i_ff_b1 = (const float*)d_in[21];
  const float* i_ff_w2 = (const float*)d_in[22];
  const float* i_ff_b2 = (const float*)d_in[23];
  const float* a_ff_w1 = (const float*)d_in[24];
  const float* a_ff_b1 = (const float*)d_in[25];
  const float* a_ff_w2 = (const float*)d_in[26];
  const float* a_ff_b2 = (const float*)d_in[27];
  float* outp = (float*)d_out;
  char* ws = (char*)d_ws;

  u16* Wqkv_t = (u16*)(ws + 0);
  u16* Wqkv_i = (u16*)(ws + 6291456);
  u16* Wqkv_a = (u16*)(ws + 15728640);
  u16* Wout_t = (u16*)(ws + 18874368);
  u16* Wout_i = (u16*)(ws + 20971520);
  u16* Wout_a = (u16*)(ws + 24117248);
  u16* Wff1_i = (u16*)(ws + 25165824);
  u16* Wff2_i = (u16*)(ws + 44040192);
  u16* Wff1_a = (u16*)(ws + 62914560);
  u16* Wff2_a = (u16*)(ws + 65011712);
  char* bufA = ws + 67108864;
  char* bufB = ws + 105906176;
  u16* x_t  = (u16*)(bufA + 0);
  u16* x_i  = (u16*)(bufA + 1048576);
  u16* x_a  = (u16*)(bufA + 10485760);
  u16* obuf = (u16*)(bufA + 0);
  u16* h_i  = (u16*)(bufA + 0);
  u16* h_a  = (u16*)(bufA + 37748736);
  u16* qb = (u16*)(bufB + 0);
  u16* kb = (u16*)(bufB + 7864320);
  u16* vb = (u16*)(bufB + 15728640);
  u16* lnff_i = (u16*)(bufB + 0);
  u16* lnff_a = (u16*)(bufB + 9437184);

  const float QS = 0.125f * 1.44269504089f;

  wtrans_k<<<dim3(3072/64, 1024/64), 256, 0, stream>>>(qkv_w_t, Wqkv_t, 1024, 3072, 1024, QS);
  wtrans_k<<<dim3(3072/64, 1536/64), 256, 0, stream>>>(qkv_w_i, Wqkv_i, 1536, 3072, 1024, QS);
  wtrans_k<<<dim3(3072/64, 512/64),  256, 0, stream>>>(qkv_w_a, Wqkv_a, 512, 3072, 1024, QS);
  wtrans_k<<<dim3(1024/64, 1024/64), 256, 0, stream>>>(out_w_t, Wout_t, 1024, 1024, 0, 1.f);
  wtrans_k<<<dim3(1536/64, 1024/64), 256, 0, stream>>>(out_w_i, Wout_i, 1024, 1536, 0, 1.f);
  wtrans_k<<<dim3(512/64, 1024/64),  256, 0, stream>>>(out_w_a, Wout_a, 1024, 512, 0, 1.f);
  wtrans_k<<<dim3(6144/64, 1536/64), 256, 0, stream>>>(i_ff_w1, Wff1_i, 1536, 6144, 0, 1.f);
  wtrans_k<<<dim3(1536/64, 6144/64), 256, 0, stream>>>(i_ff_w2, Wff2_i, 6144, 1536, 0, 1.f);
  wtrans_k<<<dim3(2048/64, 512/64),  256, 0, stream>>>(a_ff_w1, Wff1_a, 512, 2048, 0, 1.f);
  wtrans_k<<<dim3(512/64, 2048/64),  256, 0, stream>>>(a_ff_w2, Wff2_a, 2048, 512, 0, 1.f);

  ln_k<<<512, 256, 0, stream>>>(text, t_g, t_b, x_t, 1024);
  ln_k<<<3072, 256, 0, stream>>>(image, i_g, i_b, x_i, 1536);
  ln_k<<<256, 256, 0, stream>>>(action, a_g, a_b, x_a, 512);

  GemmArgs ga;
  ga.bias = nullptr; ga.resid = nullptr; ga.outF = nullptr; ga.outB = nullptr;
  ga.q = qb; ga.kk = kb; ga.v = vb;
  ga.A = x_t; ga.W = Wqkv_t; ga.M = 512;  ga.N = 3072; ga.K = 1024; ga.Nm = 256;  ga.tokoff = 0;    ga.cswz = 1;
  gemm_k<0, 64><<<dim3(48, 4), 256, 0, stream>>>(ga);
  // QKV-image: 256x128 8-wave tile
  ga.A = x_i; ga.W = Wqkv_i; ga.M = 3072; ga.N = 3072; ga.K = 1536; ga.Nm = 1536; ga.tokoff = 256;  ga.cswz = 0;
  gemm3_k<0><<<dim3(24, 12), 512, 0, stream>>>(ga);
  ga.A = x_a; ga.W = Wqkv_a; ga.M = 256;  ga.N = 3072; ga.K = 512;  ga.Nm = 128;  ga.tokoff = 1792; ga.cswz = 1;
  gemm_k<0, 64><<<dim3(48, 2), 256, 0, stream>>>(ga);

  attn_k<<<dim3(15, 32), 256, 0, stream>>>(qb, kb, vb, obuf);

  ga.q = nullptr; ga.kk = nullptr; ga.v = nullptr;
  ga.A = obuf; ga.W = Wout_t; ga.M = 512;  ga.N = 1024; ga.K = 1024; ga.Nm = 256;  ga.tokoff = 0;   ga.cswz = 1;
  ga.resid = text;   ga.outF = outp;
  gemm_k<1, 64><<<dim3(16, 4), 256, 0, stream>>>(ga);
  ga.A = obuf; ga.W = Wout_i; ga.M = 3072; ga.N = 1536; ga.K = 1024; ga.Nm = 1536; ga.tokoff = 256; ga.cswz = 0;
  ga.resid = image;  ga.outF = outp + 524288;
  gemm_k<1, 64><<<dim3(24, 24), 256, 0, stream>>>(ga);
  ga.A = obuf; ga.W = Wout_a; ga.M = 256;  ga.N = 512;  ga.K = 1024; ga.Nm = 128;  ga.tokoff = 1792; ga.cswz = 1;
  ga.resid = action; ga.outF = outp + 5242880;
  gemm_k<1, 64><<<dim3(8, 2), 256, 0, stream>>>(ga);

  ln_k<<<3072, 256, 0, stream>>>(outp + 524288, i_ffg, i_ffb, lnff_i, 1536);
  ln_k<<<256, 256, 0, stream>>>(outp + 5242880, a_ffg, a_ffb, lnff_a, 512);

  ga.resid = nullptr; ga.outF = nullptr;
  // FF1-image: 256x128 8-wave tile
  ga.A = lnff_i; ga.W = Wff1_i; ga.M = 3072; ga.N = 6144; ga.K = 1536; ga.bias = i_ff_b1; ga.outB = h_i; ga.cswz = 1;
  gemm3_k<2><<<dim3(48, 12), 512, 0, stream>>>(ga);
  ga.A = lnff_a; ga.W = Wff1_a; ga.M = 256;  ga.N = 2048; ga.K = 512;  ga.bias = a_ff_b1; ga.outB = h_a; ga.cswz = 1;
  gemm_k<2, 64><<<dim3(32, 2), 256, 0, stream>>>(ga);

  // FF2-image: plain BN=128 (best measured config for this shape)
  ga.outB = nullptr;
  ga.A = h_i; ga.W = Wff2_i; ga.M = 3072; ga.N = 1536; ga.K = 6144; ga.bias = i_ff_b2; ga.outF = outp + 524288; ga.cswz = 0;
  gemm_k<3, 128><<<dim3(12, 24), 256, 0, stream>>>(ga);
  ga.A = h_a; ga.W = Wff2_a; ga.M = 256;  ga.N = 512;  ga.K = 2048; ga.bias = a_ff_b2; ga.outF = outp + 5242880; ga.cswz = 1;
  gemm_k<3, 64><<<dim3(8, 2), 256, 0, stream>>>(ga);
}

// Round 13
// 485.645 us; speedup vs baseline: 1.0751x; 1.0751x over previous
//
#include <hip/hip_runtime.h>

typedef unsigned short u16;
typedef unsigned int u32;
typedef __bf16 bf16x8 __attribute__((ext_vector_type(8)));
typedef float f32x4 __attribute__((ext_vector_type(4)));
typedef float f32x16 __attribute__((ext_vector_type(16)));
typedef u16 u16x8 __attribute__((ext_vector_type(8)));
typedef u32 u32x4 __attribute__((ext_vector_type(4)));

// ---------------- helpers ----------------
__device__ __forceinline__ u16 f2bf(float f) {
  union { float f; unsigned u; } x; x.f = f;
  unsigned r = x.u + 0x7FFFu + ((x.u >> 16) & 1u);
  return (u16)(r >> 16);
}
__device__ __forceinline__ float bf2f(u16 h) {
  union { unsigned u; float f; } x; x.u = ((unsigned)h) << 16;
  return x.f;
}
__device__ __forceinline__ void gload_lds16(const void* gptr, const void* lptr) {
  int m0v = __builtin_amdgcn_readfirstlane((int)(unsigned)(size_t)lptr);
  asm volatile("s_mov_b32 m0, %0\n\t"
               "global_load_lds_dwordx4 %1, off\n\t"
               :: "s"(m0v), "v"(gptr) : "memory");
}
__device__ __forceinline__ f32x16 zero16() {
  f32x16 x;
#pragma unroll
  for (int i = 0; i < 16; ++i) x[i] = 0.f;
  return x;
}

// ---------------- fused weight transpose+convert: f32 [K][N] -> bf16 [N][K] x 10 jobs --------
struct WtJobs {
  const float* src[10];
  u16* dst[10];
  int K[10], N[10], qcols[10];
  float qscale[10];
  int tile0[11];
  int njobs;
};
__global__ __launch_bounds__(256) void wtrans_all_k(WtJobs j) {
  __shared__ u16 tile[64 * 72];
  int tb = blockIdx.x;
  int jb = 0;
  while (jb + 1 < j.njobs && tb >= j.tile0[jb + 1]) ++jb;
  int lt = tb - j.tile0[jb];
  int K = j.K[jb], N = j.N[jb];
  int ntn = N >> 6;
  int nb = (lt % ntn) << 6, kb = (lt / ntn) << 6;
  float sc = (nb < j.qcols[jb]) ? j.qscale[jb] : 1.f;
  const float* in = j.src[jb];
  u16* out = j.dst[jb];

  int t = threadIdx.x;
  int cg = t & 15, r0 = t >> 4;
  for (int i = 0; i < 4; ++i) {
    int k = r0 + (i << 4);
    float4 v = *reinterpret_cast<const float4*>(in + (size_t)(kb + k) * N + nb + (cg << 2));
    tile[(cg * 4 + 0) * 72 + k] = f2bf(v.x * sc);
    tile[(cg * 4 + 1) * 72 + k] = f2bf(v.y * sc);
    tile[(cg * 4 + 2) * 72 + k] = f2bf(v.z * sc);
    tile[(cg * 4 + 3) * 72 + k] = f2bf(v.w * sc);
  }
  __syncthreads();
  int kg = t & 7, n0 = t >> 3;
  for (int i = 0; i < 2; ++i) {
    int n = n0 + (i << 5);
    u16x8 val = *reinterpret_cast<const u16x8*>(&tile[n * 72 + (kg << 3)]);
    *reinterpret_cast<u16x8*>(out + (size_t)(nb + n) * K + kb + (kg << 3)) = val;
  }
}

// ---------------- fused LayerNorm: f32 [R][D] -> bf16 [R][D], up to 3 jobs ----------------
struct LnJobs {
  const float* x[3];
  const float* g[3];
  const float* b[3];
  u16* out[3];
  int D[3];
  int row0[4];
  int njobs;
};
__global__ __launch_bounds__(256) void ln_all_k(LnJobs j) {
  int blk = blockIdx.x;
  int jb = 0;
  while (jb + 1 < j.njobs && blk >= j.row0[jb + 1]) ++jb;
  int row = blk - j.row0[jb];
  int D = j.D[jb];
  const float* xr = j.x[jb] + (size_t)row * D;
  const float* gam = j.g[jb];
  const float* bet = j.b[jb];
  u16* orow = j.out[jb] + (size_t)row * D;

  int t = threadIdx.x;
  int E = D >> 8;
  float v[8];
  float s = 0.f, sq = 0.f;
  for (int i = 0; i < E; ++i) {
    float f = xr[t + (i << 8)];
    v[i] = f; s += f; sq += f * f;
  }
  for (int m = 32; m; m >>= 1) { s += __shfl_xor(s, m); sq += __shfl_xor(sq, m); }
  __shared__ float red[10];
  int wid = t >> 6;
  if ((t & 63) == 0) { red[wid] = s; red[wid + 4] = sq; }
  __syncthreads();
  if (t == 0) {
    float S = red[0] + red[1] + red[2] + red[3];
    float Q = red[4] + red[5] + red[6] + red[7];
    float mean = S / (float)D;
    float var = Q / (float)D - mean * mean;
    red[8] = mean; red[9] = rsqrtf(var + 1e-5f);
  }
  __syncthreads();
  float mean = red[8], rstd = red[9];
  for (int i = 0; i < E; ++i) {
    int idx = t + (i << 8);
    orow[idx] = f2bf((v[i] - mean) * rstd * gam[idx] + bet[idx]);
  }
}

// ---------------- GEMM: C[M][N] = A[M][K](bf16) @ Wt[N][K](bf16)^T, 128xBN tile --------------
// 3-buffer 2-ahead pipeline, counted vmcnt, raw barriers, slot-XOR swizzle
// (conflict-free), XCD-chunked swizzle. BN in {128, 64}.
struct GemmArgs {
  const u16* A; const u16* W;
  int M, N, K;
  int Nm, tokoff;
  const float* bias;
  const float* resid;
  float* outF;
  u16* outB;
  u16* q; u16* kk; u16* v;
  int cswz;
};
__device__ __forceinline__ int maprow_o(int r, int Nm, int tokoff) {
  int b = (r >= Nm) ? 1 : 0;
  return b * 1920 + tokoff + (r - b * Nm);
}

template <int MODE, int BN>
__global__ __launch_bounds__(256) void gemm_k(GemmArgs g) {
  constexpr int NF = BN / 32;
  __shared__ u16 As[3][128 * 32];
  __shared__ u16 Ws[3][BN * 32];
  int t = threadIdx.x, lane = t & 63, wid = t >> 6;

  int nwg = gridDim.x * gridDim.y;
  int wgid = blockIdx.y * gridDim.x + blockIdx.x;
  int q8 = nwg >> 3, r8 = nwg & 7;
  int xcd = wgid & 7, loc = wgid >> 3;
  int nid = (xcd < r8 ? xcd * (q8 + 1) : r8 * (q8 + 1) + (xcd - r8) * q8) + loc;
  constexpr int BNSH = (BN == 128) ? 7 : 6;
  int bm, bn;
  if (g.cswz) { bn = (nid / gridDim.y) << BNSH; bm = (nid % gridDim.y) << 7; }
  else        { bm = (nid / gridDim.x) << 7;    bn = (nid % gridDim.x) << BNSH; }

  int wr = wid >> 1, wc = wid & 1;
  int fr = lane & 15, fq = lane >> 4;

  f32x4 z = {0.f, 0.f, 0.f, 0.f};
  f32x4 acc[4][NF];
#pragma unroll
  for (int m = 0; m < 4; ++m)
#pragma unroll
    for (int n = 0; n < NF; ++n) acc[m][n] = z;

  int srow = wid * 16 + (lane >> 2);
  int scolz = (((lane & 3) ^ ((lane >> 3) & 3)) << 3);
  int ar0 = bm + srow, ar1 = bm + srow + 64;
  if (MODE == 1) { ar0 = maprow_o(ar0, g.Nm, g.tokoff); ar1 = maprow_o(ar1, g.Nm, g.tokoff); }
  const u16* Ap0 = g.A + (size_t)ar0 * g.K + scolz;
  const u16* Ap1 = g.A + (size_t)ar1 * g.K + scolz;
  const u16* Wp0 = g.W + (size_t)(bn + srow) * g.K + scolz;
  const u16* Wp1 = g.W + (size_t)(bn + srow + 64) * g.K + scolz;
  const int soff = (wid * 16) * 32;

  const int sl8 = ((fq ^ ((fr >> 1) & 3)) << 3);

#define STAGE(buf, kt)                                                    \
  do {                                                                    \
    gload_lds16(Ap0 + ((kt) << 5), &As[buf][soff]);                       \
    gload_lds16(Ap1 + ((kt) << 5), &As[buf][soff + 64 * 32]);             \
    gload_lds16(Wp0 + ((kt) << 5), &Ws[buf][soff]);                       \
    if constexpr (BN == 128)                                              \
      gload_lds16(Wp1 + ((kt) << 5), &Ws[buf][soff + 64 * 32]);           \
  } while (0)

  int nk = g.K >> 5;
  STAGE(0, 0);
  STAGE(1, 1);
  int cur = 0, stg = 2;
  for (int kt = 0; kt < nk; ++kt) {
    if (kt + 1 < nk) {
      if constexpr (BN == 128) asm volatile("s_waitcnt vmcnt(4)" ::: "memory");
      else                     asm volatile("s_waitcnt vmcnt(3)" ::: "memory");
    } else {
      asm volatile("s_waitcnt vmcnt(0)" ::: "memory");
    }
    __builtin_amdgcn_s_barrier();
    if (kt + 2 < nk) STAGE(stg, kt + 2);
    bf16x8 af[4], bw[NF];
#pragma unroll
    for (int m = 0; m < 4; ++m)
      af[m] = *reinterpret_cast<const bf16x8*>(&As[cur][(wr * 64 + m * 16 + fr) * 32 + sl8]);
#pragma unroll
    for (int n = 0; n < NF; ++n)
      bw[n] = *reinterpret_cast<const bf16x8*>(&Ws[cur][(wc * (BN / 2) + n * 16 + fr) * 32 + sl8]);
    __builtin_amdgcn_s_setprio(1);
#pragma unroll
    for (int m = 0; m < 4; ++m)
#pragma unroll
      for (int n = 0; n < NF; ++n)
        acc[m][n] = __builtin_amdgcn_mfma_f32_16x16x32_bf16(af[m], bw[n], acc[m][n], 0, 0, 0);
    __builtin_amdgcn_s_setprio(0);
    asm volatile("s_waitcnt lgkmcnt(0)" ::: "memory");
    __builtin_amdgcn_sched_barrier(0);
    cur = (cur == 2) ? 0 : cur + 1;
    stg = (stg == 2) ? 0 : stg + 1;
  }
#undef STAGE

#pragma unroll
  for (int m = 0; m < 4; ++m) {
    int rrel = wr * 64 + m * 16 + fq * 4;
#pragma unroll
    for (int n = 0; n < NF; ++n) {
      int c = bn + wc * (BN / 2) + n * 16 + fr;
#pragma unroll
      for (int j = 0; j < 4; ++j) {
        int r = bm + rrel + j;
        float val = acc[m][n][j];
        if constexpr (MODE == 0) {
          int b = (r >= g.Nm) ? 1 : 0;
          int ng = g.tokoff + (r - b * g.Nm);
          int p = c >> 10, h = (c >> 6) & 15, dh = c & 63;
          u16* dst = (p == 0) ? g.q : (p == 1) ? g.kk : g.v;
          dst[(((size_t)(b * 16 + h)) * 1920 + ng) * 64 + dh] = f2bf(val);
        } else if constexpr (MODE == 1) {
          size_t idx = (size_t)r * g.N + c;
          g.outF[idx] = g.resid[idx] + val;
        } else if constexpr (MODE == 2) {
          float hh = val + g.bias[c];
          float ge = 0.5f * hh * (1.f + erff(hh * 0.70710678118f));
          g.outB[(size_t)r * g.N + c] = f2bf(ge);
        } else {
          size_t idx = (size_t)r * g.N + c;
          g.outF[idx] += val + g.bias[c];
        }
      }
    }
  }
}

// ---------------- flash attention (swapped-operand, 32x32x16 MFMA) ----------------
__global__ __launch_bounds__(256) void attn_k(const u16* __restrict__ qg,
                                              const u16* __restrict__ kg,
                                              const u16* __restrict__ vg,
                                              u16* __restrict__ og) {
  __shared__ u16 Ks[2][64 * 64];
  __shared__ u16 Vt[2][64 * 64];
  int t = threadIdx.x, lane = t & 63, w = t >> 6;
  int h = lane >> 5, li = lane & 31;
  int qt = blockIdx.x, bh = blockIdx.y;
  const u16* qh = qg + (size_t)bh * 1920 * 64;
  const u16* kh = kg + (size_t)bh * 1920 * 64;
  const u16* vh = vg + (size_t)bh * 1920 * 64;

  bf16x8 bq[4];
  {
    int qrow = qt * 128 + w * 32 + li;
#pragma unroll
    for (int c = 0; c < 4; ++c)
      bq[c] = *reinterpret_cast<const bf16x8*>(qh + (size_t)qrow * 64 + c * 16 + h * 8);
  }

  int r = t >> 3;
  int c8 = (t & 7) << 3;
  int kswz = ((t & 7) ^ (r & 7)) << 3;

  {
    u16x8 k0 = *reinterpret_cast<const u16x8*>(kh + (size_t)r * 64 + c8);
    u16x8 k1 = *reinterpret_cast<const u16x8*>(kh + (size_t)(32 + r) * 64 + c8);
    u16x8 v0 = *reinterpret_cast<const u16x8*>(vh + (size_t)r * 64 + c8);
    u16x8 v1 = *reinterpret_cast<const u16x8*>(vh + (size_t)(32 + r) * 64 + c8);
    *reinterpret_cast<u16x8*>(&Ks[0][r * 64 + kswz]) = k0;
    *reinterpret_cast<u16x8*>(&Ks[0][(32 + r) * 64 + kswz]) = k1;
#pragma unroll
    for (int i = 0; i < 8; ++i) {
      int d = c8 + i;
      Vt[0][d * 64 + (((r >> 3) ^ i) << 3) + (r & 7)] = v0[i];
      Vt[0][d * 64 + ((((r >> 3) + 4) ^ i) << 3) + (r & 7)] = v1[i];
    }
  }
  __syncthreads();

  float m_s = -1e30f, l_s = 0.f;
  f32x16 of0 = zero16(), of1 = zero16();

  int cur = 0;
  for (int kt = 0; kt < 30; ++kt) {
    bool notlast = (kt < 29);
    u16x8 kn0, kn1, vn0, vn1;
    if (notlast) {
      const u16* kp = kh + ((size_t)((kt + 1) * 64) + r) * 64 + c8;
      const u16* vp = vh + ((size_t)((kt + 1) * 64) + r) * 64 + c8;
      kn0 = *reinterpret_cast<const u16x8*>(kp);
      kn1 = *reinterpret_cast<const u16x8*>(kp + 32 * 64);
      vn0 = *reinterpret_cast<const u16x8*>(vp);
      vn1 = *reinterpret_cast<const u16x8*>(vp + 32 * 64);
    }

    f32x16 s0 = zero16(), s1 = zero16();
#pragma unroll
    for (int c = 0; c < 4; ++c) {
      int slot = ((c * 2 + h) ^ (li & 7)) << 3;
      bf16x8 ak0 = *reinterpret_cast<const bf16x8*>(&Ks[cur][li * 64 + slot]);
      bf16x8 ak1 = *reinterpret_cast<const bf16x8*>(&Ks[cur][(32 + li) * 64 + slot]);
      s0 = __builtin_amdgcn_mfma_f32_32x32x16_bf16(ak0, bq[c], s0, 0, 0, 0);
      s1 = __builtin_amdgcn_mfma_f32_32x32x16_bf16(ak1, bq[c], s1, 0, 0, 0);
    }

    float mx = s0[0];
#pragma unroll
    for (int i = 1; i < 16; ++i) mx = fmaxf(mx, s0[i]);
#pragma unroll
    for (int i = 0; i < 16; ++i) mx = fmaxf(mx, s1[i]);
    mx = fmaxf(mx, __shfl_xor(mx, 32));

    if (__any(mx > m_s + 11.5f)) {
      float mn = fmaxf(m_s, mx);
      float sc = exp2f(m_s - mn);
      m_s = mn;
      l_s *= sc;
#pragma unroll
      for (int rr = 0; rr < 16; ++rr) {
        float scr = __shfl(sc, (rr & 3) + ((rr >> 2) << 3) + (h << 2));
        of0[rr] *= scr; of1[rr] *= scr;
      }
    }
    float rs = 0.f;
#pragma unroll
    for (int i = 0; i < 16; ++i) { s0[i] = exp2f(s0[i] - m_s); rs += s0[i]; }
#pragma unroll
    for (int i = 0; i < 16; ++i) { s1[i] = exp2f(s1[i] - m_s); rs += s1[i]; }
    rs += __shfl_xor(rs, 32);
    l_s += rs;

    u32 wv[2][4][2];
#pragma unroll
    for (int g = 0; g < 4; ++g)
#pragma unroll
      for (int c2 = 0; c2 < 2; ++c2) {
        asm("v_cvt_pk_bf16_f32 %0, %1, %2"
            : "=v"(wv[0][g][c2]) : "v"(s0[4 * g + 2 * c2]), "v"(s0[4 * g + 2 * c2 + 1]));
        asm("v_cvt_pk_bf16_f32 %0, %1, %2"
            : "=v"(wv[1][g][c2]) : "v"(s1[4 * g + 2 * c2]), "v"(s1[4 * g + 2 * c2 + 1]));
      }
    u32 xr[2][2][2];
#pragma unroll
    for (int kb = 0; kb < 2; ++kb)
#pragma unroll
      for (int e = 0; e < 2; ++e)
#pragma unroll
        for (int c2 = 0; c2 < 2; ++c2) {
          u32 snd = h ? wv[kb][2 * e][c2] : wv[kb][2 * e + 1][c2];
          xr[kb][e][c2] = (u32)__shfl_xor((int)snd, 32);
        }

#pragma unroll
    for (int kc = 0; kc < 4; ++kc) {
      int kb = kc >> 1, e = kc & 1;
      u32x4 au;
      au[0] = h ? xr[kb][e][0] : wv[kb][2 * e][0];
      au[1] = h ? xr[kb][e][1] : wv[kb][2 * e][1];
      au[2] = h ? wv[kb][2 * e + 1][0] : xr[kb][e][0];
      au[3] = h ? wv[kb][2 * e + 1][1] : xr[kb][e][1];
      bf16x8 af = *reinterpret_cast<bf16x8*>(&au);
      int slot = ((kc * 2 + h) ^ (li & 7)) << 3;
      bf16x8 bv0 = *reinterpret_cast<const bf16x8*>(&Vt[cur][li * 64 + slot]);
      bf16x8 bv1 = *reinterpret_cast<const bf16x8*>(&Vt[cur][(32 + li) * 64 + slot]);
      of0 = __builtin_amdgcn_mfma_f32_32x32x16_bf16(af, bv0, of0, 0, 0, 0);
      of1 = __builtin_amdgcn_mfma_f32_32x32x16_bf16(af, bv1, of1, 0, 0, 0);
    }

    if (notlast) {
      *reinterpret_cast<u16x8*>(&Ks[cur ^ 1][r * 64 + kswz]) = kn0;
      *reinterpret_cast<u16x8*>(&Ks[cur ^ 1][(32 + r) * 64 + kswz]) = kn1;
#pragma unroll
      for (int i = 0; i < 8; ++i) {
        int d = c8 + i;
        Vt[cur ^ 1][d * 64 + (((r >> 3) ^ i) << 3) + (r & 7)] = vn0[i];
        Vt[cur ^ 1][d * 64 + ((((r >> 3) + 4) ^ i) << 3) + (r & 7)] = vn1[i];
      }
    }
    __syncthreads();
    cur ^= 1;
  }

  int b = bh >> 4, hd = bh & 15;
#pragma unroll
  for (int rr = 0; rr < 16; ++rr) {
    int qm = (rr & 3) + ((rr >> 2) << 3) + (h << 2);
    float lq = __shfl(l_s, qm);
    float inv = 1.f / lq;
    int row = qt * 128 + w * 32 + qm;
    size_t base = ((size_t)b * 1920 + row) * 1024 + hd * 64;
    og[base + li] = f2bf(of0[rr] * inv);
    og[base + 32 + li] = f2bf(of1[rr] * inv);
  }
}

// ---------------- host ----------------
extern "C" void kernel_launch(void* const* d_in, const int* in_sizes, int n_in,
                              void* d_out, int out_size, void* d_ws, size_t ws_size,
                              hipStream_t stream) {
  const float* text   = (const float*)d_in[0];
  const float* image  = (const float*)d_in[1];
  const float* action = (const float*)d_in[2];
  const float* t_g = (const float*)d_in[4];
  const float* t_b = (const float*)d_in[5];
  const float* i_g = (const float*)d_in[6];
  const float* i_b = (const float*)d_in[7];
  const float* a_g = (const float*)d_in[8];
  const float* a_b = (const float*)d_in[9];
  const float* i_ffg = (const float*)d_in[10];
  const float* i_ffb = (const float*)d_in[11];
  const float* a_ffg = (const float*)d_in[12];
  const float* a_ffb = (const float*)d_in[13];
  const float* qkv_w_t = (const float*)d_in[14];
  const float* qkv_w_i = (const float*)d_in[15];
  const float* qkv_w_a = (const float*)d_in[16];
  const float* out_w_t = (const float*)d_in[17];
  const float* out_w_i = (const float*)d_in[18];
  const float* out_w_a = (const float*)d_in[19];
  const float* i_ff_w1 = (const float*)d_in[20];
  const float* i_ff_b1 = (const float*)d_in[21];
  const float* i_ff_w2 = (const float*)d_in[22];
  const float* i_ff_b2 = (const float*)d_in[23];
  const float* a_ff_w1 = (const float*)d_in[24];
  const float* a_ff_b1 = (const float*)d_in[25];
  const float* a_ff_w2 = (const float*)d_in[26];
  const float* a_ff_b2 = (const float*)d_in[27];
  float* outp = (float*)d_out;
  char* ws = (char*)d_ws;

  u16* Wqkv_t = (u16*)(ws + 0);
  u16* Wqkv_i = (u16*)(ws + 6291456);
  u16* Wqkv_a = (u16*)(ws + 15728640);
  u16* Wout_t = (u16*)(ws + 18874368);
  u16* Wout_i = (u16*)(ws + 20971520);
  u16* Wout_a = (u16*)(ws + 24117248);
  u16* Wff1_i = (u16*)(ws + 25165824);
  u16* Wff2_i = (u16*)(ws + 44040192);
  u16* Wff1_a = (u16*)(ws + 62914560);
  u16* Wff2_a = (u16*)(ws + 65011712);
  char* bufA = ws + 67108864;
  char* bufB = ws + 105906176;
  u16* x_t  = (u16*)(bufA + 0);
  u16* x_i  = (u16*)(bufA + 1048576);
  u16* x_a  = (u16*)(bufA + 10485760);
  u16* obuf = (u16*)(bufA + 0);
  u16* h_i  = (u16*)(bufA + 0);
  u16* h_a  = (u16*)(bufA + 37748736);
  u16* qb = (u16*)(bufB + 0);
  u16* kb = (u16*)(bufB + 7864320);
  u16* vb = (u16*)(bufB + 15728640);
  u16* lnff_i = (u16*)(bufB + 0);
  u16* lnff_a = (u16*)(bufB + 9437184);

  const float QS = 0.125f * 1.44269504089f;

  // 1) fused weight transpose (10 jobs, one launch, 8192 x 64x64 tiles)
  {
    WtJobs wj;
    const float* srcs[10] = {qkv_w_t, qkv_w_i, qkv_w_a, out_w_t, out_w_i,
                             out_w_a, i_ff_w1, i_ff_w2, a_ff_w1, a_ff_w2};
    u16* dsts[10] = {Wqkv_t, Wqkv_i, Wqkv_a, Wout_t, Wout_i,
                     Wout_a, Wff1_i, Wff2_i, Wff1_a, Wff2_a};
    int Ks[10] = {1024, 1536, 512, 1024, 1024, 1024, 1536, 6144, 512, 2048};
    int Ns[10] = {3072, 3072, 3072, 1024, 1536, 512, 6144, 1536, 2048, 512};
    int qc[10] = {1024, 1024, 1024, 0, 0, 0, 0, 0, 0, 0};
    int acc = 0;
    for (int i = 0; i < 10; ++i) {
      wj.src[i] = srcs[i]; wj.dst[i] = dsts[i];
      wj.K[i] = Ks[i]; wj.N[i] = Ns[i]; wj.qcols[i] = qc[i];
      wj.qscale[i] = QS;
      wj.tile0[i] = acc;
      acc += (Ks[i] >> 6) * (Ns[i] >> 6);
    }
    wj.tile0[10] = acc;  // 8192
    wj.njobs = 10;
    wtrans_all_k<<<acc, 256, 0, stream>>>(wj);
  }

  // 2) fused attention LayerNorms (3 jobs, one launch)
  {
    LnJobs lj;
    lj.x[0] = text;  lj.g[0] = t_g; lj.b[0] = t_b; lj.out[0] = x_t; lj.D[0] = 1024;
    lj.x[1] = image; lj.g[1] = i_g; lj.b[1] = i_b; lj.out[1] = x_i; lj.D[1] = 1536;
    lj.x[2] = action;lj.g[2] = a_g; lj.b[2] = a_b; lj.out[2] = x_a; lj.D[2] = 512;
    lj.row0[0] = 0; lj.row0[1] = 512; lj.row0[2] = 3584; lj.row0[3] = 3840;
    lj.njobs = 3;
    ln_all_k<<<3840, 256, 0, stream>>>(lj);
  }

  GemmArgs ga;
  ga.bias = nullptr; ga.resid = nullptr; ga.outF = nullptr; ga.outB = nullptr;
  ga.q = qb; ga.kk = kb; ga.v = vb;
  ga.A = x_t; ga.W = Wqkv_t; ga.M = 512;  ga.N = 3072; ga.K = 1024; ga.Nm = 256;  ga.tokoff = 0;    ga.cswz = 1;
  gemm_k<0, 64><<<dim3(48, 4), 256, 0, stream>>>(ga);
  ga.A = x_i; ga.W = Wqkv_i; ga.M = 3072; ga.N = 3072; ga.K = 1536; ga.Nm = 1536; ga.tokoff = 256;  ga.cswz = 0;
  gemm_k<0, 128><<<dim3(24, 24), 256, 0, stream>>>(ga);
  ga.A = x_a; ga.W = Wqkv_a; ga.M = 256;  ga.N = 3072; ga.K = 512;  ga.Nm = 128;  ga.tokoff = 1792; ga.cswz = 1;
  gemm_k<0, 64><<<dim3(48, 2), 256, 0, stream>>>(ga);

  attn_k<<<dim3(15, 32), 256, 0, stream>>>(qb, kb, vb, obuf);

  ga.q = nullptr; ga.kk = nullptr; ga.v = nullptr;
  ga.A = obuf; ga.W = Wout_t; ga.M = 512;  ga.N = 1024; ga.K = 1024; ga.Nm = 256;  ga.tokoff = 0;   ga.cswz = 1;
  ga.resid = text;   ga.outF = outp;
  gemm_k<1, 64><<<dim3(16, 4), 256, 0, stream>>>(ga);
  ga.A = obuf; ga.W = Wout_i; ga.M = 3072; ga.N = 1536; ga.K = 1024; ga.Nm = 1536; ga.tokoff = 256; ga.cswz = 0;
  ga.resid = image;  ga.outF = outp + 524288;
  gemm_k<1, 64><<<dim3(24, 24), 256, 0, stream>>>(ga);
  ga.A = obuf; ga.W = Wout_a; ga.M = 256;  ga.N = 512;  ga.K = 1024; ga.Nm = 128;  ga.tokoff = 1792; ga.cswz = 1;
  ga.resid = action; ga.outF = outp + 5242880;
  gemm_k<1, 64><<<dim3(8, 2), 256, 0, stream>>>(ga);

  // fused FF LayerNorms (2 jobs, one launch)
  {
    LnJobs lj;
    lj.x[0] = outp + 524288;  lj.g[0] = i_ffg; lj.b[0] = i_ffb; lj.out[0] = lnff_i; lj.D[0] = 1536;
    lj.x[1] = outp + 5242880; lj.g[1] = a_ffg; lj.b[1] = a_ffb; lj.out[1] = lnff_a; lj.D[1] = 512;
    lj.x[2] = nullptr; lj.g[2] = nullptr; lj.b[2] = nullptr; lj.out[2] = nullptr; lj.D[2] = 0;
    lj.row0[0] = 0; lj.row0[1] = 3072; lj.row0[2] = 3328; lj.row0[3] = 3328;
    lj.njobs = 2;
    ln_all_k<<<3328, 256, 0, stream>>>(lj);
  }

  ga.resid = nullptr; ga.outF = nullptr;
  ga.A = lnff_i; ga.W = Wff1_i; ga.M = 3072; ga.N = 6144; ga.K = 1536; ga.bias = i_ff_b1; ga.outB = h_i; ga.cswz = 1;
  gemm_k<2, 128><<<dim3(48, 24), 256, 0, stream>>>(ga);
  ga.A = lnff_a; ga.W = Wff1_a; ga.M = 256;  ga.N = 2048; ga.K = 512;  ga.bias = a_ff_b1; ga.outB = h_a; ga.cswz = 1;
  gemm_k<2, 64><<<dim3(32, 2), 256, 0, stream>>>(ga);

  ga.outB = nullptr;
  ga.A = h_i; ga.W = Wff2_i; ga.M = 3072; ga.N = 1536; ga.K = 6144; ga.bias = i_ff_b2; ga.outF = outp + 524288; ga.cswz = 0;
  gemm_k<3, 128><<<dim3(12, 24), 256, 0, stream>>>(ga);
  ga.A = h_a; ga.W = Wff2_a; ga.M = 256;  ga.N = 512;  ga.K = 2048; ga.bias = a_ff_b2; ga.outF = outp + 5242880; ga.cswz = 1;
  gemm_k<3, 64><<<dim3(8, 2), 256, 0, stream>>>(ga);
}

// Round 14
// 415.291 us; speedup vs baseline: 1.2573x; 1.1694x over previous
//
#include <hip/hip_runtime.h>

typedef unsigned short u16;
typedef unsigned int u32;
typedef __bf16 bf16x8 __attribute__((ext_vector_type(8)));
typedef float f32x4 __attribute__((ext_vector_type(4)));
typedef float f32x16 __attribute__((ext_vector_type(16)));
typedef u16 u16x8 __attribute__((ext_vector_type(8)));
typedef u32 u32x4 __attribute__((ext_vector_type(4)));

// ---------------- helpers ----------------
__device__ __forceinline__ u16 f2bf(float f) {
  union { float f; unsigned u; } x; x.f = f;
  unsigned r = x.u + 0x7FFFu + ((x.u >> 16) & 1u);
  return (u16)(r >> 16);
}
__device__ __forceinline__ float bf2f(u16 h) {
  union { unsigned u; float f; } x; x.u = ((unsigned)h) << 16;
  return x.f;
}
__device__ __forceinline__ void gload_lds16(const void* gptr, const void* lptr) {
  int m0v = __builtin_amdgcn_readfirstlane((int)(unsigned)(size_t)lptr);
  asm volatile("s_mov_b32 m0, %0\n\t"
               "global_load_lds_dwordx4 %1, off\n\t"
               :: "s"(m0v), "v"(gptr) : "memory");
}
__device__ __forceinline__ f32x16 zero16() {
  f32x16 x;
#pragma unroll
  for (int i = 0; i < 16; ++i) x[i] = 0.f;
  return x;
}

// ---------------- fused weight transpose+convert: f32 [K][N] -> bf16 [N][K] x 10 jobs --------
struct WtJobs {
  const float* src[10];
  u16* dst[10];
  int K[10], N[10], qcols[10];
  float qscale[10];
  int tile0[11];
  int njobs;
};
__global__ __launch_bounds__(256) void wtrans_all_k(WtJobs j) {
  __shared__ u16 tile[64 * 72];
  int tb = blockIdx.x;
  int jb = 0;
  while (jb + 1 < j.njobs && tb >= j.tile0[jb + 1]) ++jb;
  int lt = tb - j.tile0[jb];
  int K = j.K[jb], N = j.N[jb];
  int ntn = N >> 6;
  int nb = (lt % ntn) << 6, kb = (lt / ntn) << 6;
  float sc = (nb < j.qcols[jb]) ? j.qscale[jb] : 1.f;
  const float* in = j.src[jb];
  u16* out = j.dst[jb];

  int t = threadIdx.x;
  int cg = t & 15, r0 = t >> 4;
  for (int i = 0; i < 4; ++i) {
    int k = r0 + (i << 4);
    float4 v = *reinterpret_cast<const float4*>(in + (size_t)(kb + k) * N + nb + (cg << 2));
    tile[(cg * 4 + 0) * 72 + k] = f2bf(v.x * sc);
    tile[(cg * 4 + 1) * 72 + k] = f2bf(v.y * sc);
    tile[(cg * 4 + 2) * 72 + k] = f2bf(v.z * sc);
    tile[(cg * 4 + 3) * 72 + k] = f2bf(v.w * sc);
  }
  __syncthreads();
  int kg = t & 7, n0 = t >> 3;
  for (int i = 0; i < 2; ++i) {
    int n = n0 + (i << 5);
    u16x8 val = *reinterpret_cast<const u16x8*>(&tile[n * 72 + (kg << 3)]);
    *reinterpret_cast<u16x8*>(out + (size_t)(nb + n) * K + kb + (kg << 3)) = val;
  }
}

// ---------------- fused LayerNorm: f32 [R][D] -> bf16 [R][D], up to 3 jobs ----------------
struct LnJobs {
  const float* x[3];
  const float* g[3];
  const float* b[3];
  u16* out[3];
  int D[3];
  int row0[4];
  int njobs;
};
__global__ __launch_bounds__(256) void ln_all_k(LnJobs j) {
  int blk = blockIdx.x;
  int jb = 0;
  while (jb + 1 < j.njobs && blk >= j.row0[jb + 1]) ++jb;
  int row = blk - j.row0[jb];
  int D = j.D[jb];
  const float* xr = j.x[jb] + (size_t)row * D;
  const float* gam = j.g[jb];
  const float* bet = j.b[jb];
  u16* orow = j.out[jb] + (size_t)row * D;

  int t = threadIdx.x;
  int E = D >> 8;
  float v[8];
  float s = 0.f, sq = 0.f;
  for (int i = 0; i < E; ++i) {
    float f = xr[t + (i << 8)];
    v[i] = f; s += f; sq += f * f;
  }
  for (int m = 32; m; m >>= 1) { s += __shfl_xor(s, m); sq += __shfl_xor(sq, m); }
  __shared__ float red[10];
  int wid = t >> 6;
  if ((t & 63) == 0) { red[wid] = s; red[wid + 4] = sq; }
  __syncthreads();
  if (t == 0) {
    float S = red[0] + red[1] + red[2] + red[3];
    float Q = red[4] + red[5] + red[6] + red[7];
    float mean = S / (float)D;
    float var = Q / (float)D - mean * mean;
    red[8] = mean; red[9] = rsqrtf(var + 1e-5f);
  }
  __syncthreads();
  float mean = red[8], rstd = red[9];
  for (int i = 0; i < E; ++i) {
    int idx = t + (i << 8);
    orow[idx] = f2bf((v[i] - mean) * rstd * gam[idx] + bet[idx]);
  }
}

// ---------------- grouped GEMM: up to 3 independent jobs per launch ----------------
// Per-job: C[M][N] = A[M][K](bf16) @ Wt[N][K](bf16)^T, 128xBN tile, 3-buffer 2-ahead
// pipeline, counted vmcnt, raw barriers, slot-XOR swizzle, per-job XCD-chunked swizzle.
// MODE 0: QKV scatter   MODE 1: resid + acc -> f32 (A rows via maprow)
// MODE 2: gelu(acc+bias) -> bf16   MODE 3: outF += acc + bias
struct GemmArgs {
  const u16* A; const u16* W;
  int M, N, K;
  int Nm, tokoff;
  const float* bias;
  const float* resid;
  float* outF;
  u16* outB;
  u16* q; u16* kk; u16* v;
  int cswz;
};
struct GemmJobs {
  GemmArgs a[3];
  int gx[3], gy[3];
  int blk0[4];
  int njobs;
};
__device__ __forceinline__ int maprow_o(int r, int Nm, int tokoff) {
  int b = (r >= Nm) ? 1 : 0;
  return b * 1920 + tokoff + (r - b * Nm);
}

template <int MODE, int BN>
__global__ __launch_bounds__(256) void gemmg_k(GemmJobs j) {
  constexpr int NF = BN / 32;
  __shared__ u16 As[3][128 * 32];
  __shared__ u16 Ws[3][BN * 32];
  int t = threadIdx.x, lane = t & 63, wid = t >> 6;

  int blk = blockIdx.x;
  int jb = 0;
  while (jb + 1 < j.njobs && blk >= j.blk0[jb + 1]) ++jb;
  GemmArgs g = j.a[jb];
  int gx = j.gx[jb], gy = j.gy[jb];
  int wgid = blk - j.blk0[jb];

  int nwg = gx * gy;
  int q8 = nwg >> 3, r8 = nwg & 7;
  int xcd = wgid & 7, loc = wgid >> 3;
  int nid = (xcd < r8 ? xcd * (q8 + 1) : r8 * (q8 + 1) + (xcd - r8) * q8) + loc;
  constexpr int BNSH = (BN == 128) ? 7 : 6;
  int bm, bn;
  if (g.cswz) { bn = (nid / gy) << BNSH; bm = (nid % gy) << 7; }
  else        { bm = (nid / gx) << 7;    bn = (nid % gx) << BNSH; }

  int wr = wid >> 1, wc = wid & 1;
  int fr = lane & 15, fq = lane >> 4;

  f32x4 z = {0.f, 0.f, 0.f, 0.f};
  f32x4 acc[4][NF];
#pragma unroll
  for (int m = 0; m < 4; ++m)
#pragma unroll
    for (int n = 0; n < NF; ++n) acc[m][n] = z;

  int srow = wid * 16 + (lane >> 2);
  int scolz = (((lane & 3) ^ ((lane >> 3) & 3)) << 3);
  int ar0 = bm + srow, ar1 = bm + srow + 64;
  if (MODE == 1) { ar0 = maprow_o(ar0, g.Nm, g.tokoff); ar1 = maprow_o(ar1, g.Nm, g.tokoff); }
  const u16* Ap0 = g.A + (size_t)ar0 * g.K + scolz;
  const u16* Ap1 = g.A + (size_t)ar1 * g.K + scolz;
  const u16* Wp0 = g.W + (size_t)(bn + srow) * g.K + scolz;
  const u16* Wp1 = g.W + (size_t)(bn + srow + 64) * g.K + scolz;
  const int soff = (wid * 16) * 32;

  const int sl8 = ((fq ^ ((fr >> 1) & 3)) << 3);

#define STAGE(buf, kt)                                                    \
  do {                                                                    \
    gload_lds16(Ap0 + ((kt) << 5), &As[buf][soff]);                       \
    gload_lds16(Ap1 + ((kt) << 5), &As[buf][soff + 64 * 32]);             \
    gload_lds16(Wp0 + ((kt) << 5), &Ws[buf][soff]);                       \
    if constexpr (BN == 128)                                              \
      gload_lds16(Wp1 + ((kt) << 5), &Ws[buf][soff + 64 * 32]);           \
  } while (0)

  int nk = g.K >> 5;
  STAGE(0, 0);
  STAGE(1, 1);
  int cur = 0, stg = 2;
  for (int kt = 0; kt < nk; ++kt) {
    if (kt + 1 < nk) {
      if constexpr (BN == 128) asm volatile("s_waitcnt vmcnt(4)" ::: "memory");
      else                     asm volatile("s_waitcnt vmcnt(3)" ::: "memory");
    } else {
      asm volatile("s_waitcnt vmcnt(0)" ::: "memory");
    }
    __builtin_amdgcn_s_barrier();
    if (kt + 2 < nk) STAGE(stg, kt + 2);
    bf16x8 af[4], bw[NF];
#pragma unroll
    for (int m = 0; m < 4; ++m)
      af[m] = *reinterpret_cast<const bf16x8*>(&As[cur][(wr * 64 + m * 16 + fr) * 32 + sl8]);
#pragma unroll
    for (int n = 0; n < NF; ++n)
      bw[n] = *reinterpret_cast<const bf16x8*>(&Ws[cur][(wc * (BN / 2) + n * 16 + fr) * 32 + sl8]);
    __builtin_amdgcn_s_setprio(1);
#pragma unroll
    for (int m = 0; m < 4; ++m)
#pragma unroll
      for (int n = 0; n < NF; ++n)
        acc[m][n] = __builtin_amdgcn_mfma_f32_16x16x32_bf16(af[m], bw[n], acc[m][n], 0, 0, 0);
    __builtin_amdgcn_s_setprio(0);
    asm volatile("s_waitcnt lgkmcnt(0)" ::: "memory");
    __builtin_amdgcn_sched_barrier(0);
    cur = (cur == 2) ? 0 : cur + 1;
    stg = (stg == 2) ? 0 : stg + 1;
  }
#undef STAGE

#pragma unroll
  for (int m = 0; m < 4; ++m) {
    int rrel = wr * 64 + m * 16 + fq * 4;
#pragma unroll
    for (int n = 0; n < NF; ++n) {
      int c = bn + wc * (BN / 2) + n * 16 + fr;
#pragma unroll
      for (int jj = 0; jj < 4; ++jj) {
        int r = bm + rrel + jj;
        float val = acc[m][n][jj];
        if constexpr (MODE == 0) {
          int b = (r >= g.Nm) ? 1 : 0;
          int ng = g.tokoff + (r - b * g.Nm);
          int p = c >> 10, h = (c >> 6) & 15, dh = c & 63;
          u16* dst = (p == 0) ? g.q : (p == 1) ? g.kk : g.v;
          dst[(((size_t)(b * 16 + h)) * 1920 + ng) * 64 + dh] = f2bf(val);
        } else if constexpr (MODE == 1) {
          size_t idx = (size_t)r * g.N + c;
          g.outF[idx] = g.resid[idx] + val;
        } else if constexpr (MODE == 2) {
          float hh = val + g.bias[c];
          float ge = 0.5f * hh * (1.f + erff(hh * 0.70710678118f));
          g.outB[(size_t)r * g.N + c] = f2bf(ge);
        } else {
          size_t idx = (size_t)r * g.N + c;
          g.outF[idx] += val + g.bias[c];
        }
      }
    }
  }
}

// ---------------- flash attention (swapped-operand, 32x32x16 MFMA) ----------------
__global__ __launch_bounds__(256) void attn_k(const u16* __restrict__ qg,
                                              const u16* __restrict__ kg,
                                              const u16* __restrict__ vg,
                                              u16* __restrict__ og) {
  __shared__ u16 Ks[2][64 * 64];
  __shared__ u16 Vt[2][64 * 64];
  int t = threadIdx.x, lane = t & 63, w = t >> 6;
  int h = lane >> 5, li = lane & 31;
  int qt = blockIdx.x, bh = blockIdx.y;
  const u16* qh = qg + (size_t)bh * 1920 * 64;
  const u16* kh = kg + (size_t)bh * 1920 * 64;
  const u16* vh = vg + (size_t)bh * 1920 * 64;

  bf16x8 bq[4];
  {
    int qrow = qt * 128 + w * 32 + li;
#pragma unroll
    for (int c = 0; c < 4; ++c)
      bq[c] = *reinterpret_cast<const bf16x8*>(qh + (size_t)qrow * 64 + c * 16 + h * 8);
  }

  int r = t >> 3;
  int c8 = (t & 7) << 3;
  int kswz = ((t & 7) ^ (r & 7)) << 3;

  {
    u16x8 k0 = *reinterpret_cast<const u16x8*>(kh + (size_t)r * 64 + c8);
    u16x8 k1 = *reinterpret_cast<const u16x8*>(kh + (size_t)(32 + r) * 64 + c8);
    u16x8 v0 = *reinterpret_cast<const u16x8*>(vh + (size_t)r * 64 + c8);
    u16x8 v1 = *reinterpret_cast<const u16x8*>(vh + (size_t)(32 + r) * 64 + c8);
    *reinterpret_cast<u16x8*>(&Ks[0][r * 64 + kswz]) = k0;
    *reinterpret_cast<u16x8*>(&Ks[0][(32 + r) * 64 + kswz]) = k1;
#pragma unroll
    for (int i = 0; i < 8; ++i) {
      int d = c8 + i;
      Vt[0][d * 64 + (((r >> 3) ^ i) << 3) + (r & 7)] = v0[i];
      Vt[0][d * 64 + ((((r >> 3) + 4) ^ i) << 3) + (r & 7)] = v1[i];
    }
  }
  __syncthreads();

  float m_s = -1e30f, l_s = 0.f;
  f32x16 of0 = zero16(), of1 = zero16();

  int cur = 0;
  for (int kt = 0; kt < 30; ++kt) {
    bool notlast = (kt < 29);
    u16x8 kn0, kn1, vn0, vn1;
    if (notlast) {
      const u16* kp = kh + ((size_t)((kt + 1) * 64) + r) * 64 + c8;
      const u16* vp = vh + ((size_t)((kt + 1) * 64) + r) * 64 + c8;
      kn0 = *reinterpret_cast<const u16x8*>(kp);
      kn1 = *reinterpret_cast<const u16x8*>(kp + 32 * 64);
      vn0 = *reinterpret_cast<const u16x8*>(vp);
      vn1 = *reinterpret_cast<const u16x8*>(vp + 32 * 64);
    }

    f32x16 s0 = zero16(), s1 = zero16();
#pragma unroll
    for (int c = 0; c < 4; ++c) {
      int slot = ((c * 2 + h) ^ (li & 7)) << 3;
      bf16x8 ak0 = *reinterpret_cast<const bf16x8*>(&Ks[cur][li * 64 + slot]);
      bf16x8 ak1 = *reinterpret_cast<const bf16x8*>(&Ks[cur][(32 + li) * 64 + slot]);
      s0 = __builtin_amdgcn_mfma_f32_32x32x16_bf16(ak0, bq[c], s0, 0, 0, 0);
      s1 = __builtin_amdgcn_mfma_f32_32x32x16_bf16(ak1, bq[c], s1, 0, 0, 0);
    }

    float mx = s0[0];
#pragma unroll
    for (int i = 1; i < 16; ++i) mx = fmaxf(mx, s0[i]);
#pragma unroll
    for (int i = 0; i < 16; ++i) mx = fmaxf(mx, s1[i]);
    mx = fmaxf(mx, __shfl_xor(mx, 32));

    if (__any(mx > m_s + 11.5f)) {
      float mn = fmaxf(m_s, mx);
      float sc = exp2f(m_s - mn);
      m_s = mn;
      l_s *= sc;
#pragma unroll
      for (int rr = 0; rr < 16; ++rr) {
        float scr = __shfl(sc, (rr & 3) + ((rr >> 2) << 3) + (h << 2));
        of0[rr] *= scr; of1[rr] *= scr;
      }
    }
    float rs = 0.f;
#pragma unroll
    for (int i = 0; i < 16; ++i) { s0[i] = exp2f(s0[i] - m_s); rs += s0[i]; }
#pragma unroll
    for (int i = 0; i < 16; ++i) { s1[i] = exp2f(s1[i] - m_s); rs += s1[i]; }
    rs += __shfl_xor(rs, 32);
    l_s += rs;

    u32 wv[2][4][2];
#pragma unroll
    for (int g = 0; g < 4; ++g)
#pragma unroll
      for (int c2 = 0; c2 < 2; ++c2) {
        asm("v_cvt_pk_bf16_f32 %0, %1, %2"
            : "=v"(wv[0][g][c2]) : "v"(s0[4 * g + 2 * c2]), "v"(s0[4 * g + 2 * c2 + 1]));
        asm("v_cvt_pk_bf16_f32 %0, %1, %2"
            : "=v"(wv[1][g][c2]) : "v"(s1[4 * g + 2 * c2]), "v"(s1[4 * g + 2 * c2 + 1]));
      }
    u32 xr[2][2][2];
#pragma unroll
    for (int kb = 0; kb < 2; ++kb)
#pragma unroll
      for (int e = 0; e < 2; ++e)
#pragma unroll
        for (int c2 = 0; c2 < 2; ++c2) {
          u32 snd = h ? wv[kb][2 * e][c2] : wv[kb][2 * e + 1][c2];
          xr[kb][e][c2] = (u32)__shfl_xor((int)snd, 32);
        }

#pragma unroll
    for (int kc = 0; kc < 4; ++kc) {
      int kb = kc >> 1, e = kc & 1;
      u32x4 au;
      au[0] = h ? xr[kb][e][0] : wv[kb][2 * e][0];
      au[1] = h ? xr[kb][e][1] : wv[kb][2 * e][1];
      au[2] = h ? wv[kb][2 * e + 1][0] : xr[kb][e][0];
      au[3] = h ? wv[kb][2 * e + 1][1] : xr[kb][e][1];
      bf16x8 af = *reinterpret_cast<bf16x8*>(&au);
      int slot = ((kc * 2 + h) ^ (li & 7)) << 3;
      bf16x8 bv0 = *reinterpret_cast<const bf16x8*>(&Vt[cur][li * 64 + slot]);
      bf16x8 bv1 = *reinterpret_cast<const bf16x8*>(&Vt[cur][(32 + li) * 64 + slot]);
      of0 = __builtin_amdgcn_mfma_f32_32x32x16_bf16(af, bv0, of0, 0, 0, 0);
      of1 = __builtin_amdgcn_mfma_f32_32x32x16_bf16(af, bv1, of1, 0, 0, 0);
    }

    if (notlast) {
      *reinterpret_cast<u16x8*>(&Ks[cur ^ 1][r * 64 + kswz]) = kn0;
      *reinterpret_cast<u16x8*>(&Ks[cur ^ 1][(32 + r) * 64 + kswz]) = kn1;
#pragma unroll
      for (int i = 0; i < 8; ++i) {
        int d = c8 + i;
        Vt[cur ^ 1][d * 64 + (((r >> 3) ^ i) << 3) + (r & 7)] = vn0[i];
        Vt[cur ^ 1][d * 64 + ((((r >> 3) + 4) ^ i) << 3) + (r & 7)] = vn1[i];
      }
    }
    __syncthreads();
    cur ^= 1;
  }

  int b = bh >> 4, hd = bh & 15;
#pragma unroll
  for (int rr = 0; rr < 16; ++rr) {
    int qm = (rr & 3) + ((rr >> 2) << 3) + (h << 2);
    float lq = __shfl(l_s, qm);
    float inv = 1.f / lq;
    int row = qt * 128 + w * 32 + qm;
    size_t base = ((size_t)b * 1920 + row) * 1024 + hd * 64;
    og[base + li] = f2bf(of0[rr] * inv);
    og[base + 32 + li] = f2bf(of1[rr] * inv);
  }
}

// ---------------- host ----------------
extern "C" void kernel_launch(void* const* d_in, const int* in_sizes, int n_in,
                              void* d_out, int out_size, void* d_ws, size_t ws_size,
                              hipStream_t stream) {
  const float* text   = (const float*)d_in[0];
  const float* image  = (const float*)d_in[1];
  const float* action = (const float*)d_in[2];
  const float* t_g = (const float*)d_in[4];
  const float* t_b = (const float*)d_in[5];
  const float* i_g = (const float*)d_in[6];
  const float* i_b = (const float*)d_in[7];
  const float* a_g = (const float*)d_in[8];
  const float* a_b = (const float*)d_in[9];
  const float* i_ffg = (const float*)d_in[10];
  const float* i_ffb = (const float*)d_in[11];
  const float* a_ffg = (const float*)d_in[12];
  const float* a_ffb = (const float*)d_in[13];
  const float* qkv_w_t = (const float*)d_in[14];
  const float* qkv_w_i = (const float*)d_in[15];
  const float* qkv_w_a = (const float*)d_in[16];
  const float* out_w_t = (const float*)d_in[17];
  const float* out_w_i = (const float*)d_in[18];
  const float* out_w_a = (const float*)d_in[19];
  const float* i_ff_w1 = (const float*)d_in[20];
  const float* i_ff_b1 = (const float*)d_in[21];
  const float* i_ff_w2 = (const float*)d_in[22];
  const float* i_ff_b2 = (const float*)d_in[23];
  const float* a_ff_w1 = (const float*)d_in[24];
  const float* a_ff_b1 = (const float*)d_in[25];
  const float* a_ff_w2 = (const float*)d_in[26];
  const float* a_ff_b2 = (const float*)d_in[27];
  float* outp = (float*)d_out;
  char* ws = (char*)d_ws;

  u16* Wqkv_t = (u16*)(ws + 0);
  u16* Wqkv_i = (u16*)(ws + 6291456);
  u16* Wqkv_a = (u16*)(ws + 15728640);
  u16* Wout_t = (u16*)(ws + 18874368);
  u16* Wout_i = (u16*)(ws + 20971520);
  u16* Wout_a = (u16*)(ws + 24117248);
  u16* Wff1_i = (u16*)(ws + 25165824);
  u16* Wff2_i = (u16*)(ws + 44040192);
  u16* Wff1_a = (u16*)(ws + 62914560);
  u16* Wff2_a = (u16*)(ws + 65011712);
  char* bufA = ws + 67108864;
  char* bufB = ws + 105906176;
  u16* x_t  = (u16*)(bufA + 0);
  u16* x_i  = (u16*)(bufA + 1048576);
  u16* x_a  = (u16*)(bufA + 10485760);
  u16* obuf = (u16*)(bufA + 0);
  u16* h_i  = (u16*)(bufA + 0);
  u16* h_a  = (u16*)(bufA + 37748736);
  u16* qb = (u16*)(bufB + 0);
  u16* kb = (u16*)(bufB + 7864320);
  u16* vb = (u16*)(bufB + 15728640);
  u16* lnff_i = (u16*)(bufB + 0);
  u16* lnff_a = (u16*)(bufB + 9437184);

  const float QS = 0.125f * 1.44269504089f;

  // 1) fused weight transpose (10 jobs, one launch)
  {
    WtJobs wj;
    const float* srcs[10] = {qkv_w_t, qkv_w_i, qkv_w_a, out_w_t, out_w_i,
                             out_w_a, i_ff_w1, i_ff_w2, a_ff_w1, a_ff_w2};
    u16* dsts[10] = {Wqkv_t, Wqkv_i, Wqkv_a, Wout_t, Wout_i,
                     Wout_a, Wff1_i, Wff2_i, Wff1_a, Wff2_a};
    int Ks[10] = {1024, 1536, 512, 1024, 1024, 1024, 1536, 6144, 512, 2048};
    int Ns[10] = {3072, 3072, 3072, 1024, 1536, 512, 6144, 1536, 2048, 512};
    int qc[10] = {1024, 1024, 1024, 0, 0, 0, 0, 0, 0, 0};
    int acc = 0;
    for (int i = 0; i < 10; ++i) {
      wj.src[i] = srcs[i]; wj.dst[i] = dsts[i];
      wj.K[i] = Ks[i]; wj.N[i] = Ns[i]; wj.qcols[i] = qc[i];
      wj.qscale[i] = QS;
      wj.tile0[i] = acc;
      acc += (Ks[i] >> 6) * (Ns[i] >> 6);
    }
    wj.tile0[10] = acc;
    wj.njobs = 10;
    wtrans_all_k<<<acc, 256, 0, stream>>>(wj);
  }

  // 2) fused attention LayerNorms
  {
    LnJobs lj;
    lj.x[0] = text;  lj.g[0] = t_g; lj.b[0] = t_b; lj.out[0] = x_t; lj.D[0] = 1024;
    lj.x[1] = image; lj.g[1] = i_g; lj.b[1] = i_b; lj.out[1] = x_i; lj.D[1] = 1536;
    lj.x[2] = action;lj.g[2] = a_g; lj.b[2] = a_b; lj.out[2] = x_a; lj.D[2] = 512;
    lj.row0[0] = 0; lj.row0[1] = 512; lj.row0[2] = 3584; lj.row0[3] = 3840;
    lj.njobs = 3;
    ln_all_k<<<3840, 256, 0, stream>>>(lj);
  }

  // 3) QKV: grouped (t, i, a), MODE 0, BN=128  [96 + 576 + 48 = 720 blocks]
  {
    GemmJobs gj;
    for (int i = 0; i < 3; ++i) {
      gj.a[i].bias = nullptr; gj.a[i].resid = nullptr;
      gj.a[i].outF = nullptr; gj.a[i].outB = nullptr;
      gj.a[i].q = qb; gj.a[i].kk = kb; gj.a[i].v = vb;
    }
    gj.a[0].A = x_t; gj.a[0].W = Wqkv_t; gj.a[0].M = 512;  gj.a[0].N = 3072; gj.a[0].K = 1024;
    gj.a[0].Nm = 256;  gj.a[0].tokoff = 0;    gj.a[0].cswz = 1; gj.gx[0] = 24; gj.gy[0] = 4;
    gj.a[1].A = x_i; gj.a[1].W = Wqkv_i; gj.a[1].M = 3072; gj.a[1].N = 3072; gj.a[1].K = 1536;
    gj.a[1].Nm = 1536; gj.a[1].tokoff = 256;  gj.a[1].cswz = 0; gj.gx[1] = 24; gj.gy[1] = 24;
    gj.a[2].A = x_a; gj.a[2].W = Wqkv_a; gj.a[2].M = 256;  gj.a[2].N = 3072; gj.a[2].K = 512;
    gj.a[2].Nm = 128;  gj.a[2].tokoff = 1792; gj.a[2].cswz = 1; gj.gx[2] = 24; gj.gy[2] = 2;
    gj.blk0[0] = 0; gj.blk0[1] = 96; gj.blk0[2] = 672; gj.blk0[3] = 720;
    gj.njobs = 3;
    gemmg_k<0, 128><<<720, 256, 0, stream>>>(gj);
  }

  // 4) attention
  attn_k<<<dim3(15, 32), 256, 0, stream>>>(qb, kb, vb, obuf);

  // 5) out-projections: grouped (t, i, a), MODE 1, BN=64  [64 + 576 + 16 = 656 blocks]
  {
    GemmJobs gj;
    for (int i = 0; i < 3; ++i) {
      gj.a[i].bias = nullptr; gj.a[i].outB = nullptr;
      gj.a[i].q = nullptr; gj.a[i].kk = nullptr; gj.a[i].v = nullptr;
      gj.a[i].A = obuf; gj.a[i].K = 1024;
    }
    gj.a[0].W = Wout_t; gj.a[0].M = 512;  gj.a[0].N = 1024; gj.a[0].Nm = 256;  gj.a[0].tokoff = 0;
    gj.a[0].resid = text;   gj.a[0].outF = outp;           gj.a[0].cswz = 1; gj.gx[0] = 16; gj.gy[0] = 4;
    gj.a[1].W = Wout_i; gj.a[1].M = 3072; gj.a[1].N = 1536; gj.a[1].Nm = 1536; gj.a[1].tokoff = 256;
    gj.a[1].resid = image;  gj.a[1].outF = outp + 524288;  gj.a[1].cswz = 0; gj.gx[1] = 24; gj.gy[1] = 24;
    gj.a[2].W = Wout_a; gj.a[2].M = 256;  gj.a[2].N = 512;  gj.a[2].Nm = 128;  gj.a[2].tokoff = 1792;
    gj.a[2].resid = action; gj.a[2].outF = outp + 5242880; gj.a[2].cswz = 1; gj.gx[2] = 8;  gj.gy[2] = 2;
    gj.blk0[0] = 0; gj.blk0[1] = 64; gj.blk0[2] = 640; gj.blk0[3] = 656;
    gj.njobs = 3;
    gemmg_k<1, 64><<<656, 256, 0, stream>>>(gj);
  }

  // 6) fused FF LayerNorms
  {
    LnJobs lj;
    lj.x[0] = outp + 524288;  lj.g[0] = i_ffg; lj.b[0] = i_ffb; lj.out[0] = lnff_i; lj.D[0] = 1536;
    lj.x[1] = outp + 5242880; lj.g[1] = a_ffg; lj.b[1] = a_ffb; lj.out[1] = lnff_a; lj.D[1] = 512;
    lj.x[2] = nullptr; lj.g[2] = nullptr; lj.b[2] = nullptr; lj.out[2] = nullptr; lj.D[2] = 0;
    lj.row0[0] = 0; lj.row0[1] = 3072; lj.row0[2] = 3328; lj.row0[3] = 3328;
    lj.njobs = 2;
    ln_all_k<<<3328, 256, 0, stream>>>(lj);
  }

  // 7) FF1: grouped (i, a), MODE 2, BN=128  [1152 + 32 = 1184 blocks]
  {
    GemmJobs gj;
    for (int i = 0; i < 2; ++i) {
      gj.a[i].resid = nullptr; gj.a[i].outF = nullptr;
      gj.a[i].q = nullptr; gj.a[i].kk = nullptr; gj.a[i].v = nullptr;
      gj.a[i].Nm = 0; gj.a[i].tokoff = 0;
    }
    gj.a[0].A = lnff_i; gj.a[0].W = Wff1_i; gj.a[0].M = 3072; gj.a[0].N = 6144; gj.a[0].K = 1536;
    gj.a[0].bias = i_ff_b1; gj.a[0].outB = h_i; gj.a[0].cswz = 1; gj.gx[0] = 48; gj.gy[0] = 24;
    gj.a[1].A = lnff_a; gj.a[1].W = Wff1_a; gj.a[1].M = 256;  gj.a[1].N = 2048; gj.a[1].K = 512;
    gj.a[1].bias = a_ff_b1; gj.a[1].outB = h_a; gj.a[1].cswz = 1; gj.gx[1] = 16; gj.gy[1] = 2;
    gj.a[2] = gj.a[1];
    gj.blk0[0] = 0; gj.blk0[1] = 1152; gj.blk0[2] = 1184; gj.blk0[3] = 1184;
    gj.gx[2] = gj.gx[1]; gj.gy[2] = gj.gy[1];
    gj.njobs = 2;
    gemmg_k<2, 128><<<1184, 256, 0, stream>>>(gj);
  }

  // 8) FF2: grouped (i, a), MODE 3, BN=128  [288 + 8 = 296 blocks]
  {
    GemmJobs gj;
    for (int i = 0; i < 2; ++i) {
      gj.a[i].resid = nullptr; gj.a[i].outB = nullptr;
      gj.a[i].q = nullptr; gj.a[i].kk = nullptr; gj.a[i].v = nullptr;
      gj.a[i].Nm = 0; gj.a[i].tokoff = 0;
    }
    gj.a[0].A = h_i; gj.a[0].W = Wff2_i; gj.a[0].M = 3072; gj.a[0].N = 1536; gj.a[0].K = 6144;
    gj.a[0].bias = i_ff_b2; gj.a[0].outF = outp + 524288;  gj.a[0].cswz = 0; gj.gx[0] = 12; gj.gy[0] = 24;
    gj.a[1].A = h_a; gj.a[1].W = Wff2_a; gj.a[1].M = 256;  gj.a[1].N = 512;  gj.a[1].K = 2048;
    gj.a[1].bias = a_ff_b2; gj.a[1].outF = outp + 5242880; gj.a[1].cswz = 1; gj.gx[1] = 4;  gj.gy[1] = 2;
    gj.a[2] = gj.a[1];
    gj.blk0[0] = 0; gj.blk0[1] = 288; gj.blk0[2] = 296; gj.blk0[3] = 296;
    gj.gx[2] = gj.gx[1]; gj.gy[2] = gj.gy[1];
    gj.njobs = 2;
    gemmg_k<3, 128><<<296, 256, 0, stream>>>(gj);
  }
}

// Round 15
// 403.228 us; speedup vs baseline: 1.2949x; 1.0299x over previous
//
#include <hip/hip_runtime.h>

typedef unsigned short u16;
typedef unsigned int u32;
typedef __bf16 bf16x8 __attribute__((ext_vector_type(8)));
typedef float f32x4 __attribute__((ext_vector_type(4)));
typedef float f32x16 __attribute__((ext_vector_type(16)));
typedef u16 u16x8 __attribute__((ext_vector_type(8)));
typedef u32 u32x4 __attribute__((ext_vector_type(4)));

// ---------------- helpers ----------------
__device__ __forceinline__ u16 f2bf(float f) {
  union { float f; unsigned u; } x; x.f = f;
  unsigned r = x.u + 0x7FFFu + ((x.u >> 16) & 1u);
  return (u16)(r >> 16);
}
__device__ __forceinline__ float bf2f(u16 h) {
  union { unsigned u; float f; } x; x.u = ((unsigned)h) << 16;
  return x.f;
}
__device__ __forceinline__ void gload_lds16(const void* gptr, const void* lptr) {
  int m0v = __builtin_amdgcn_readfirstlane((int)(unsigned)(size_t)lptr);
  asm volatile("s_mov_b32 m0, %0\n\t"
               "global_load_lds_dwordx4 %1, off\n\t"
               :: "s"(m0v), "v"(gptr) : "memory");
}
__device__ __forceinline__ f32x16 zero16() {
  f32x16 x;
#pragma unroll
  for (int i = 0; i < 16; ++i) x[i] = 0.f;
  return x;
}

// ---------------- fused weight transpose+convert: f32 [K][N] -> bf16 [N][K] x 10 jobs --------
struct WtJobs {
  const float* src[10];
  u16* dst[10];
  int K[10], N[10], qcols[10];
  float qscale[10];
  int tile0[11];
  int njobs;
};
__global__ __launch_bounds__(256) void wtrans_all_k(WtJobs j) {
  __shared__ u16 tile[64 * 72];
  int tb = blockIdx.x;
  int jb = 0;
  while (jb + 1 < j.njobs && tb >= j.tile0[jb + 1]) ++jb;
  int lt = tb - j.tile0[jb];
  int K = j.K[jb], N = j.N[jb];
  int ntn = N >> 6;
  int nb = (lt % ntn) << 6, kb = (lt / ntn) << 6;
  float sc = (nb < j.qcols[jb]) ? j.qscale[jb] : 1.f;
  const float* in = j.src[jb];
  u16* out = j.dst[jb];

  int t = threadIdx.x;
  int cg = t & 15, r0 = t >> 4;
  for (int i = 0; i < 4; ++i) {
    int k = r0 + (i << 4);
    float4 v = *reinterpret_cast<const float4*>(in + (size_t)(kb + k) * N + nb + (cg << 2));
    tile[(cg * 4 + 0) * 72 + k] = f2bf(v.x * sc);
    tile[(cg * 4 + 1) * 72 + k] = f2bf(v.y * sc);
    tile[(cg * 4 + 2) * 72 + k] = f2bf(v.z * sc);
    tile[(cg * 4 + 3) * 72 + k] = f2bf(v.w * sc);
  }
  __syncthreads();
  int kg = t & 7, n0 = t >> 3;
  for (int i = 0; i < 2; ++i) {
    int n = n0 + (i << 5);
    u16x8 val = *reinterpret_cast<const u16x8*>(&tile[n * 72 + (kg << 3)]);
    *reinterpret_cast<u16x8*>(out + (size_t)(nb + n) * K + kb + (kg << 3)) = val;
  }
}

// ---------------- fused LayerNorm: f32 [R][D] -> bf16 [R][D], up to 3 jobs ----------------
struct LnJobs {
  const float* x[3];
  const float* g[3];
  const float* b[3];
  u16* out[3];
  int D[3];
  int row0[4];
  int njobs;
};
__global__ __launch_bounds__(256) void ln_all_k(LnJobs j) {
  int blk = blockIdx.x;
  int jb = 0;
  while (jb + 1 < j.njobs && blk >= j.row0[jb + 1]) ++jb;
  int row = blk - j.row0[jb];
  int D = j.D[jb];
  const float* xr = j.x[jb] + (size_t)row * D;
  const float* gam = j.g[jb];
  const float* bet = j.b[jb];
  u16* orow = j.out[jb] + (size_t)row * D;

  int t = threadIdx.x;
  int E = D >> 8;
  float v[8];
  float s = 0.f, sq = 0.f;
  for (int i = 0; i < E; ++i) {
    float f = xr[t + (i << 8)];
    v[i] = f; s += f; sq += f * f;
  }
  for (int m = 32; m; m >>= 1) { s += __shfl_xor(s, m); sq += __shfl_xor(sq, m); }
  __shared__ float red[10];
  int wid = t >> 6;
  if ((t & 63) == 0) { red[wid] = s; red[wid + 4] = sq; }
  __syncthreads();
  if (t == 0) {
    float S = red[0] + red[1] + red[2] + red[3];
    float Q = red[4] + red[5] + red[6] + red[7];
    float mean = S / (float)D;
    float var = Q / (float)D - mean * mean;
    red[8] = mean; red[9] = rsqrtf(var + 1e-5f);
  }
  __syncthreads();
  float mean = red[8], rstd = red[9];
  for (int i = 0; i < E; ++i) {
    int idx = t + (i << 8);
    orow[idx] = f2bf((v[i] - mean) * rstd * gam[idx] + bet[idx]);
  }
}

// ---------------- grouped GEMM: up to 3 independent jobs per launch ----------------
// NBUF-buffer (NBUF-1)-ahead pipeline, counted vmcnt, raw barriers, slot-XOR swizzle,
// per-job XCD-chunked swizzle. NBUF=5 for grid-starved large-K shapes (more bytes in
// flight covers L2 latency); NBUF=3 elsewhere (occupancy).
struct GemmArgs {
  const u16* A; const u16* W;
  int M, N, K;
  int Nm, tokoff;
  const float* bias;
  const float* resid;
  float* outF;
  u16* outB;
  u16* q; u16* kk; u16* v;
  int cswz;
};
struct GemmJobs {
  GemmArgs a[3];
  int gx[3], gy[3];
  int blk0[4];
  int njobs;
};
__device__ __forceinline__ int maprow_o(int r, int Nm, int tokoff) {
  int b = (r >= Nm) ? 1 : 0;
  return b * 1920 + tokoff + (r - b * Nm);
}

template <int MODE, int BN, int NBUF>
__global__ __launch_bounds__(256) void gemmg_k(GemmJobs j) {
  constexpr int NF = BN / 32;
  __shared__ u16 As[NBUF][128 * 32];
  __shared__ u16 Ws[NBUF][BN * 32];
  int t = threadIdx.x, lane = t & 63, wid = t >> 6;

  int blk = blockIdx.x;
  int jb = 0;
  while (jb + 1 < j.njobs && blk >= j.blk0[jb + 1]) ++jb;
  GemmArgs g = j.a[jb];
  int gx = j.gx[jb], gy = j.gy[jb];
  int wgid = blk - j.blk0[jb];

  int nwg = gx * gy;
  int q8 = nwg >> 3, r8 = nwg & 7;
  int xcd = wgid & 7, loc = wgid >> 3;
  int nid = (xcd < r8 ? xcd * (q8 + 1) : r8 * (q8 + 1) + (xcd - r8) * q8) + loc;
  constexpr int BNSH = (BN == 128) ? 7 : 6;
  int bm, bn;
  if (g.cswz) { bn = (nid / gy) << BNSH; bm = (nid % gy) << 7; }
  else        { bm = (nid / gx) << 7;    bn = (nid % gx) << BNSH; }

  int wr = wid >> 1, wc = wid & 1;
  int fr = lane & 15, fq = lane >> 4;

  f32x4 z = {0.f, 0.f, 0.f, 0.f};
  f32x4 acc[4][NF];
#pragma unroll
  for (int m = 0; m < 4; ++m)
#pragma unroll
    for (int n = 0; n < NF; ++n) acc[m][n] = z;

  int srow = wid * 16 + (lane >> 2);
  int scolz = (((lane & 3) ^ ((lane >> 3) & 3)) << 3);
  int ar0 = bm + srow, ar1 = bm + srow + 64;
  if (MODE == 1) { ar0 = maprow_o(ar0, g.Nm, g.tokoff); ar1 = maprow_o(ar1, g.Nm, g.tokoff); }
  const u16* Ap0 = g.A + (size_t)ar0 * g.K + scolz;
  const u16* Ap1 = g.A + (size_t)ar1 * g.K + scolz;
  const u16* Wp0 = g.W + (size_t)(bn + srow) * g.K + scolz;
  const u16* Wp1 = g.W + (size_t)(bn + srow + 64) * g.K + scolz;
  const int soff = (wid * 16) * 32;

  const int sl8 = ((fq ^ ((fr >> 1) & 3)) << 3);

#define STAGE(buf, kt)                                                    \
  do {                                                                    \
    gload_lds16(Ap0 + ((kt) << 5), &As[buf][soff]);                       \
    gload_lds16(Ap1 + ((kt) << 5), &As[buf][soff + 64 * 32]);             \
    gload_lds16(Wp0 + ((kt) << 5), &Ws[buf][soff]);                       \
    if constexpr (BN == 128)                                              \
      gload_lds16(Wp1 + ((kt) << 5), &Ws[buf][soff + 64 * 32]);           \
  } while (0)

  int nk = g.K >> 5;
  for (int i = 0; i < NBUF - 1; ++i) STAGE(i, i);
  int cur = 0, stg = NBUF - 1;
  for (int kt = 0; kt < nk; ++kt) {
    int ahead = nk - 1 - kt;
    if constexpr (NBUF == 5) {
      if (ahead >= 3)      asm volatile("s_waitcnt vmcnt(12)" ::: "memory");
      else if (ahead == 2) asm volatile("s_waitcnt vmcnt(8)" ::: "memory");
      else if (ahead == 1) asm volatile("s_waitcnt vmcnt(4)" ::: "memory");
      else                 asm volatile("s_waitcnt vmcnt(0)" ::: "memory");
    } else {
      if (ahead >= 1) {
        if constexpr (BN == 128) asm volatile("s_waitcnt vmcnt(4)" ::: "memory");
        else                     asm volatile("s_waitcnt vmcnt(3)" ::: "memory");
      } else {
        asm volatile("s_waitcnt vmcnt(0)" ::: "memory");
      }
    }
    __builtin_amdgcn_s_barrier();
    if (kt + NBUF - 1 < nk) STAGE(stg, kt + NBUF - 1);
    bf16x8 af[4], bw[NF];
#pragma unroll
    for (int m = 0; m < 4; ++m)
      af[m] = *reinterpret_cast<const bf16x8*>(&As[cur][(wr * 64 + m * 16 + fr) * 32 + sl8]);
#pragma unroll
    for (int n = 0; n < NF; ++n)
      bw[n] = *reinterpret_cast<const bf16x8*>(&Ws[cur][(wc * (BN / 2) + n * 16 + fr) * 32 + sl8]);
    __builtin_amdgcn_s_setprio(1);
#pragma unroll
    for (int m = 0; m < 4; ++m)
#pragma unroll
      for (int n = 0; n < NF; ++n)
        acc[m][n] = __builtin_amdgcn_mfma_f32_16x16x32_bf16(af[m], bw[n], acc[m][n], 0, 0, 0);
    __builtin_amdgcn_s_setprio(0);
    asm volatile("s_waitcnt lgkmcnt(0)" ::: "memory");
    __builtin_amdgcn_sched_barrier(0);
    cur = (cur == NBUF - 1) ? 0 : cur + 1;
    stg = (stg == NBUF - 1) ? 0 : stg + 1;
  }
#undef STAGE

#pragma unroll
  for (int m = 0; m < 4; ++m) {
    int rrel = wr * 64 + m * 16 + fq * 4;
#pragma unroll
    for (int n = 0; n < NF; ++n) {
      int c = bn + wc * (BN / 2) + n * 16 + fr;
#pragma unroll
      for (int jj = 0; jj < 4; ++jj) {
        int r = bm + rrel + jj;
        float val = acc[m][n][jj];
        if constexpr (MODE == 0) {
          int b = (r >= g.Nm) ? 1 : 0;
          int ng = g.tokoff + (r - b * g.Nm);
          int p = c >> 10, h = (c >> 6) & 15, dh = c & 63;
          u16* dst = (p == 0) ? g.q : (p == 1) ? g.kk : g.v;
          dst[(((size_t)(b * 16 + h)) * 1920 + ng) * 64 + dh] = f2bf(val);
        } else if constexpr (MODE == 1) {
          size_t idx = (size_t)r * g.N + c;
          g.outF[idx] = g.resid[idx] + val;
        } else if constexpr (MODE == 2) {
          float hh = val + g.bias[c];
          float ge = 0.5f * hh * (1.f + erff(hh * 0.70710678118f));
          g.outB[(size_t)r * g.N + c] = f2bf(ge);
        } else {
          size_t idx = (size_t)r * g.N + c;
          g.outF[idx] += val + g.bias[c];
        }
      }
    }
  }
}

// ---------------- flash attention (swapped-operand, 32x32x16 MFMA) ----------------
__global__ __launch_bounds__(256) void attn_k(const u16* __restrict__ qg,
                                              const u16* __restrict__ kg,
                                              const u16* __restrict__ vg,
                                              u16* __restrict__ og) {
  __shared__ u16 Ks[2][64 * 64];
  __shared__ u16 Vt[2][64 * 64];
  int t = threadIdx.x, lane = t & 63, w = t >> 6;
  int h = lane >> 5, li = lane & 31;
  int qt = blockIdx.x, bh = blockIdx.y;
  const u16* qh = qg + (size_t)bh * 1920 * 64;
  const u16* kh = kg + (size_t)bh * 1920 * 64;
  const u16* vh = vg + (size_t)bh * 1920 * 64;

  bf16x8 bq[4];
  {
    int qrow = qt * 128 + w * 32 + li;
#pragma unroll
    for (int c = 0; c < 4; ++c)
      bq[c] = *reinterpret_cast<const bf16x8*>(qh + (size_t)qrow * 64 + c * 16 + h * 8);
  }

  int r = t >> 3;
  int c8 = (t & 7) << 3;
  int kswz = ((t & 7) ^ (r & 7)) << 3;

  {
    u16x8 k0 = *reinterpret_cast<const u16x8*>(kh + (size_t)r * 64 + c8);
    u16x8 k1 = *reinterpret_cast<const u16x8*>(kh + (size_t)(32 + r) * 64 + c8);
    u16x8 v0 = *reinterpret_cast<const u16x8*>(vh + (size_t)r * 64 + c8);
    u16x8 v1 = *reinterpret_cast<const u16x8*>(vh + (size_t)(32 + r) * 64 + c8);
    *reinterpret_cast<u16x8*>(&Ks[0][r * 64 + kswz]) = k0;
    *reinterpret_cast<u16x8*>(&Ks[0][(32 + r) * 64 + kswz]) = k1;
#pragma unroll
    for (int i = 0; i < 8; ++i) {
      int d = c8 + i;
      Vt[0][d * 64 + (((r >> 3) ^ i) << 3) + (r & 7)] = v0[i];
      Vt[0][d * 64 + ((((r >> 3) + 4) ^ i) << 3) + (r & 7)] = v1[i];
    }
  }
  __syncthreads();

  float m_s = -1e30f, l_s = 0.f;
  f32x16 of0 = zero16(), of1 = zero16();

  int cur = 0;
  for (int kt = 0; kt < 30; ++kt) {
    bool notlast = (kt < 29);
    u16x8 kn0, kn1, vn0, vn1;
    if (notlast) {
      const u16* kp = kh + ((size_t)((kt + 1) * 64) + r) * 64 + c8;
      const u16* vp = vh + ((size_t)((kt + 1) * 64) + r) * 64 + c8;
      kn0 = *reinterpret_cast<const u16x8*>(kp);
      kn1 = *reinterpret_cast<const u16x8*>(kp + 32 * 64);
      vn0 = *reinterpret_cast<const u16x8*>(vp);
      vn1 = *reinterpret_cast<const u16x8*>(vp + 32 * 64);
    }

    f32x16 s0 = zero16(), s1 = zero16();
    __builtin_amdgcn_s_setprio(1);
#pragma unroll
    for (int c = 0; c < 4; ++c) {
      int slot = ((c * 2 + h) ^ (li & 7)) << 3;
      bf16x8 ak0 = *reinterpret_cast<const bf16x8*>(&Ks[cur][li * 64 + slot]);
      bf16x8 ak1 = *reinterpret_cast<const bf16x8*>(&Ks[cur][(32 + li) * 64 + slot]);
      s0 = __builtin_amdgcn_mfma_f32_32x32x16_bf16(ak0, bq[c], s0, 0, 0, 0);
      s1 = __builtin_amdgcn_mfma_f32_32x32x16_bf16(ak1, bq[c], s1, 0, 0, 0);
    }
    __builtin_amdgcn_s_setprio(0);

    float mx = s0[0];
#pragma unroll
    for (int i = 1; i < 16; ++i) mx = fmaxf(mx, s0[i]);
#pragma unroll
    for (int i = 0; i < 16; ++i) mx = fmaxf(mx, s1[i]);
    mx = fmaxf(mx, __shfl_xor(mx, 32));

    if (__any(mx > m_s + 11.5f)) {
      float mn = fmaxf(m_s, mx);
      float sc = exp2f(m_s - mn);
      m_s = mn;
      l_s *= sc;
#pragma unroll
      for (int rr = 0; rr < 16; ++rr) {
        float scr = __shfl(sc, (rr & 3) + ((rr >> 2) << 3) + (h << 2));
        of0[rr] *= scr; of1[rr] *= scr;
      }
    }
    float rs = 0.f;
#pragma unroll
    for (int i = 0; i < 16; ++i) { s0[i] = exp2f(s0[i] - m_s); rs += s0[i]; }
#pragma unroll
    for (int i = 0; i < 16; ++i) { s1[i] = exp2f(s1[i] - m_s); rs += s1[i]; }
    rs += __shfl_xor(rs, 32);
    l_s += rs;

    u32 wv[2][4][2];
#pragma unroll
    for (int g = 0; g < 4; ++g)
#pragma unroll
      for (int c2 = 0; c2 < 2; ++c2) {
        asm("v_cvt_pk_bf16_f32 %0, %1, %2"
            : "=v"(wv[0][g][c2]) : "v"(s0[4 * g + 2 * c2]), "v"(s0[4 * g + 2 * c2 + 1]));
        asm("v_cvt_pk_bf16_f32 %0, %1, %2"
            : "=v"(wv[1][g][c2]) : "v"(s1[4 * g + 2 * c2]), "v"(s1[4 * g + 2 * c2 + 1]));
      }
    u32 xr[2][2][2];
#pragma unroll
    for (int kb = 0; kb < 2; ++kb)
#pragma unroll
      for (int e = 0; e < 2; ++e)
#pragma unroll
        for (int c2 = 0; c2 < 2; ++c2) {
          u32 snd = h ? wv[kb][2 * e][c2] : wv[kb][2 * e + 1][c2];
          xr[kb][e][c2] = (u32)__shfl_xor((int)snd, 32);
        }

    __builtin_amdgcn_s_setprio(1);
#pragma unroll
    for (int kc = 0; kc < 4; ++kc) {
      int kb = kc >> 1, e = kc & 1;
      u32x4 au;
      au[0] = h ? xr[kb][e][0] : wv[kb][2 * e][0];
      au[1] = h ? xr[kb][e][1] : wv[kb][2 * e][1];
      au[2] = h ? wv[kb][2 * e + 1][0] : xr[kb][e][0];
      au[3] = h ? wv[kb][2 * e + 1][1] : xr[kb][e][1];
      bf16x8 af = *reinterpret_cast<bf16x8*>(&au);
      int slot = ((kc * 2 + h) ^ (li & 7)) << 3;
      bf16x8 bv0 = *reinterpret_cast<const bf16x8*>(&Vt[cur][li * 64 + slot]);
      bf16x8 bv1 = *reinterpret_cast<const bf16x8*>(&Vt[cur][(32 + li) * 64 + slot]);
      of0 = __builtin_amdgcn_mfma_f32_32x32x16_bf16(af, bv0, of0, 0, 0, 0);
      of1 = __builtin_amdgcn_mfma_f32_32x32x16_bf16(af, bv1, of1, 0, 0, 0);
    }
    __builtin_amdgcn_s_setprio(0);

    if (notlast) {
      *reinterpret_cast<u16x8*>(&Ks[cur ^ 1][r * 64 + kswz]) = kn0;
      *reinterpret_cast<u16x8*>(&Ks[cur ^ 1][(32 + r) * 64 + kswz]) = kn1;
#pragma unroll
      for (int i = 0; i < 8; ++i) {
        int d = c8 + i;
        Vt[cur ^ 1][d * 64 + (((r >> 3) ^ i) << 3) + (r & 7)] = vn0[i];
        Vt[cur ^ 1][d * 64 + ((((r >> 3) + 4) ^ i) << 3) + (r & 7)] = vn1[i];
      }
    }
    __syncthreads();
    cur ^= 1;
  }

  int b = bh >> 4, hd = bh & 15;
#pragma unroll
  for (int rr = 0; rr < 16; ++rr) {
    int qm = (rr & 3) + ((rr >> 2) << 3) + (h << 2);
    float lq = __shfl(l_s, qm);
    float inv = 1.f / lq;
    int row = qt * 128 + w * 32 + qm;
    size_t base = ((size_t)b * 1920 + row) * 1024 + hd * 64;
    og[base + li] = f2bf(of0[rr] * inv);
    og[base + 32 + li] = f2bf(of1[rr] * inv);
  }
}

// ---------------- host ----------------
extern "C" void kernel_launch(void* const* d_in, const int* in_sizes, int n_in,
                              void* d_out, int out_size, void* d_ws, size_t ws_size,
                              hipStream_t stream) {
  const float* text   = (const float*)d_in[0];
  const float* image  = (const float*)d_in[1];
  const float* action = (const float*)d_in[2];
  const float* t_g = (const float*)d_in[4];
  const float* t_b = (const float*)d_in[5];
  const float* i_g = (const float*)d_in[6];
  const float* i_b = (const float*)d_in[7];
  const float* a_g = (const float*)d_in[8];
  const float* a_b = (const float*)d_in[9];
  const float* i_ffg = (const float*)d_in[10];
  const float* i_ffb = (const float*)d_in[11];
  const float* a_ffg = (const float*)d_in[12];
  const float* a_ffb = (const float*)d_in[13];
  const float* qkv_w_t = (const float*)d_in[14];
  const float* qkv_w_i = (const float*)d_in[15];
  const float* qkv_w_a = (const float*)d_in[16];
  const float* out_w_t = (const float*)d_in[17];
  const float* out_w_i = (const float*)d_in[18];
  const float* out_w_a = (const float*)d_in[19];
  const float* i_ff_w1 = (const float*)d_in[20];
  const float* i_ff_b1 = (const float*)d_in[21];
  const float* i_ff_w2 = (const float*)d_in[22];
  const float* i_ff_b2 = (const float*)d_in[23];
  const float* a_ff_w1 = (const float*)d_in[24];
  const float* a_ff_b1 = (const float*)d_in[25];
  const float* a_ff_w2 = (const float*)d_in[26];
  const float* a_ff_b2 = (const float*)d_in[27];
  float* outp = (float*)d_out;
  char* ws = (char*)d_ws;

  u16* Wqkv_t = (u16*)(ws + 0);
  u16* Wqkv_i = (u16*)(ws + 6291456);
  u16* Wqkv_a = (u16*)(ws + 15728640);
  u16* Wout_t = (u16*)(ws + 18874368);
  u16* Wout_i = (u16*)(ws + 20971520);
  u16* Wout_a = (u16*)(ws + 24117248);
  u16* Wff1_i = (u16*)(ws + 25165824);
  u16* Wff2_i = (u16*)(ws + 44040192);
  u16* Wff1_a = (u16*)(ws + 62914560);
  u16* Wff2_a = (u16*)(ws + 65011712);
  char* bufA = ws + 67108864;
  char* bufB = ws + 105906176;
  u16* x_t  = (u16*)(bufA + 0);
  u16* x_i  = (u16*)(bufA + 1048576);
  u16* x_a  = (u16*)(bufA + 10485760);
  u16* obuf = (u16*)(bufA + 0);
  u16* h_i  = (u16*)(bufA + 0);
  u16* h_a  = (u16*)(bufA + 37748736);
  u16* qb = (u16*)(bufB + 0);
  u16* kb = (u16*)(bufB + 7864320);
  u16* vb = (u16*)(bufB + 15728640);
  u16* lnff_i = (u16*)(bufB + 0);
  u16* lnff_a = (u16*)(bufB + 9437184);

  const float QS = 0.125f * 1.44269504089f;

  // 1) fused weight transpose (10 jobs, one launch)
  {
    WtJobs wj;
    const float* srcs[10] = {qkv_w_t, qkv_w_i, qkv_w_a, out_w_t, out_w_i,
                             out_w_a, i_ff_w1, i_ff_w2, a_ff_w1, a_ff_w2};
    u16* dsts[10] = {Wqkv_t, Wqkv_i, Wqkv_a, Wout_t, Wout_i,
                     Wout_a, Wff1_i, Wff2_i, Wff1_a, Wff2_a};
    int Ks[10] = {1024, 1536, 512, 1024, 1024, 1024, 1536, 6144, 512, 2048};
    int Ns[10] = {3072, 3072, 3072, 1024, 1536, 512, 6144, 1536, 2048, 512};
    int qc[10] = {1024, 1024, 1024, 0, 0, 0, 0, 0, 0, 0};
    int acc = 0;
    for (int i = 0; i < 10; ++i) {
      wj.src[i] = srcs[i]; wj.dst[i] = dsts[i];
      wj.K[i] = Ks[i]; wj.N[i] = Ns[i]; wj.qcols[i] = qc[i];
      wj.qscale[i] = QS;
      wj.tile0[i] = acc;
      acc += (Ks[i] >> 6) * (Ns[i] >> 6);
    }
    wj.tile0[10] = acc;
    wj.njobs = 10;
    wtrans_all_k<<<acc, 256, 0, stream>>>(wj);
  }

  // 2) fused attention LayerNorms
  {
    LnJobs lj;
    lj.x[0] = text;  lj.g[0] = t_g; lj.b[0] = t_b; lj.out[0] = x_t; lj.D[0] = 1024;
    lj.x[1] = image; lj.g[1] = i_g; lj.b[1] = i_b; lj.out[1] = x_i; lj.D[1] = 1536;
    lj.x[2] = action;lj.g[2] = a_g; lj.b[2] = a_b; lj.out[2] = x_a; lj.D[2] = 512;
    lj.row0[0] = 0; lj.row0[1] = 512; lj.row0[2] = 3584; lj.row0[3] = 3840;
    lj.njobs = 3;
    ln_all_k<<<3840, 256, 0, stream>>>(lj);
  }

  // 3) QKV: grouped (t, i, a), MODE 0, BN=128, depth 3  [720 blocks]
  {
    GemmJobs gj;
    for (int i = 0; i < 3; ++i) {
      gj.a[i].bias = nullptr; gj.a[i].resid = nullptr;
      gj.a[i].outF = nullptr; gj.a[i].outB = nullptr;
      gj.a[i].q = qb; gj.a[i].kk = kb; gj.a[i].v = vb;
    }
    gj.a[0].A = x_t; gj.a[0].W = Wqkv_t; gj.a[0].M = 512;  gj.a[0].N = 3072; gj.a[0].K = 1024;
    gj.a[0].Nm = 256;  gj.a[0].tokoff = 0;    gj.a[0].cswz = 1; gj.gx[0] = 24; gj.gy[0] = 4;
    gj.a[1].A = x_i; gj.a[1].W = Wqkv_i; gj.a[1].M = 3072; gj.a[1].N = 3072; gj.a[1].K = 1536;
    gj.a[1].Nm = 1536; gj.a[1].tokoff = 256;  gj.a[1].cswz = 0; gj.gx[1] = 24; gj.gy[1] = 24;
    gj.a[2].A = x_a; gj.a[2].W = Wqkv_a; gj.a[2].M = 256;  gj.a[2].N = 3072; gj.a[2].K = 512;
    gj.a[2].Nm = 128;  gj.a[2].tokoff = 1792; gj.a[2].cswz = 1; gj.gx[2] = 24; gj.gy[2] = 2;
    gj.blk0[0] = 0; gj.blk0[1] = 96; gj.blk0[2] = 672; gj.blk0[3] = 720;
    gj.njobs = 3;
    gemmg_k<0, 128, 3><<<720, 256, 0, stream>>>(gj);
  }

  // 4) attention
  attn_k<<<dim3(15, 32), 256, 0, stream>>>(qb, kb, vb, obuf);

  // 5) out-projections: grouped (t, i, a), MODE 1, BN=64, depth 3  [656 blocks]
  {
    GemmJobs gj;
    for (int i = 0; i < 3; ++i) {
      gj.a[i].bias = nullptr; gj.a[i].outB = nullptr;
      gj.a[i].q = nullptr; gj.a[i].kk = nullptr; gj.a[i].v = nullptr;
      gj.a[i].A = obuf; gj.a[i].K = 1024;
    }
    gj.a[0].W = Wout_t; gj.a[0].M = 512;  gj.a[0].N = 1024; gj.a[0].Nm = 256;  gj.a[0].tokoff = 0;
    gj.a[0].resid = text;   gj.a[0].outF = outp;           gj.a[0].cswz = 1; gj.gx[0] = 16; gj.gy[0] = 4;
    gj.a[1].W = Wout_i; gj.a[1].M = 3072; gj.a[1].N = 1536; gj.a[1].Nm = 1536; gj.a[1].tokoff = 256;
    gj.a[1].resid = image;  gj.a[1].outF = outp + 524288;  gj.a[1].cswz = 0; gj.gx[1] = 24; gj.gy[1] = 24;
    gj.a[2].W = Wout_a; gj.a[2].M = 256;  gj.a[2].N = 512;  gj.a[2].Nm = 128;  gj.a[2].tokoff = 1792;
    gj.a[2].resid = action; gj.a[2].outF = outp + 5242880; gj.a[2].cswz = 1; gj.gx[2] = 8;  gj.gy[2] = 2;
    gj.blk0[0] = 0; gj.blk0[1] = 64; gj.blk0[2] = 640; gj.blk0[3] = 656;
    gj.njobs = 3;
    gemmg_k<1, 64, 3><<<656, 256, 0, stream>>>(gj);
  }

  // 6) fused FF LayerNorms
  {
    LnJobs lj;
    lj.x[0] = outp + 524288;  lj.g[0] = i_ffg; lj.b[0] = i_ffb; lj.out[0] = lnff_i; lj.D[0] = 1536;
    lj.x[1] = outp + 5242880; lj.g[1] = a_ffg; lj.b[1] = a_ffb; lj.out[1] = lnff_a; lj.D[1] = 512;
    lj.x[2] = nullptr; lj.g[2] = nullptr; lj.b[2] = nullptr; lj.out[2] = nullptr; lj.D[2] = 0;
    lj.row0[0] = 0; lj.row0[1] = 3072; lj.row0[2] = 3328; lj.row0[3] = 3328;
    lj.njobs = 2;
    ln_all_k<<<3328, 256, 0, stream>>>(lj);
  }

  // 7) FF1: grouped (i, a), MODE 2, BN=128, depth 3  [1184 blocks]
  {
    GemmJobs gj;
    for (int i = 0; i < 2; ++i) {
      gj.a[i].resid = nullptr; gj.a[i].outF = nullptr;
      gj.a[i].q = nullptr; gj.a[i].kk = nullptr; gj.a[i].v = nullptr;
      gj.a[i].Nm = 0; gj.a[i].tokoff = 0;
    }
    gj.a[0].A = lnff_i; gj.a[0].W = Wff1_i; gj.a[0].M = 3072; gj.a[0].N = 6144; gj.a[0].K = 1536;
    gj.a[0].bias = i_ff_b1; gj.a[0].outB = h_i; gj.a[0].cswz = 1; gj.gx[0] = 48; gj.gy[0] = 24;
    gj.a[1].A = lnff_a; gj.a[1].W = Wff1_a; gj.a[1].M = 256;  gj.a[1].N = 2048; gj.a[1].K = 512;
    gj.a[1].bias = a_ff_b1; gj.a[1].outB = h_a; gj.a[1].cswz = 1; gj.gx[1] = 16; gj.gy[1] = 2;
    gj.a[2] = gj.a[1];
    gj.blk0[0] = 0; gj.blk0[1] = 1152; gj.blk0[2] = 1184; gj.blk0[3] = 1184;
    gj.gx[2] = gj.gx[1]; gj.gy[2] = gj.gy[1];
    gj.njobs = 2;
    gemmg_k<2, 128, 3><<<1184, 256, 0, stream>>>(gj);
  }

  // 8) FF2: grouped (i, a), MODE 3, BN=128, depth 5 (L2-latency coverage)  [296 blocks]
  {
    GemmJobs gj;
    for (int i = 0; i < 2; ++i) {
      gj.a[i].resid = nullptr; gj.a[i].outB = nullptr;
      gj.a[i].q = nullptr; gj.a[i].kk = nullptr; gj.a[i].v = nullptr;
      gj.a[i].Nm = 0; gj.a[i].tokoff = 0;
    }
    gj.a[0].A = h_i; gj.a[0].W = Wff2_i; gj.a[0].M = 3072; gj.a[0].N = 1536; gj.a[0].K = 6144;
    gj.a[0].bias = i_ff_b2; gj.a[0].outF = outp + 524288;  gj.a[0].cswz = 0; gj.gx[0] = 12; gj.gy[0] = 24;
    gj.a[1].A = h_a; gj.a[1].W = Wff2_a; gj.a[1].M = 256;  gj.a[1].N = 512;  gj.a[1].K = 2048;
    gj.a[1].bias = a_ff_b2; gj.a[1].outF = outp + 5242880; gj.a[1].cswz = 1; gj.gx[1] = 4;  gj.gy[1] = 2;
    gj.a[2] = gj.a[1];
    gj.blk0[0] = 0; gj.blk0[1] = 288; gj.blk0[2] = 296; gj.blk0[3] = 296;
    gj.gx[2] = gj.gx[1]; gj.gy[2] = gj.gy[1];
    gj.njobs = 2;
    gemmg_k<3, 128, 5><<<296, 256, 0, stream>>>(gj);
  }
}